// Round 6
// baseline (317.239 us; speedup 1.0000x reference)
//
#include <hip/hip_runtime.h>
#include <stdint.h>

#define S_LEN 2048
#define BATCH 2
#define DM 768
#define NH 12
#define DKH 64
#define DFF 3072
#define MROWS (BATCH * S_LEN)  // 4096

typedef short bf16x8 __attribute__((ext_vector_type(8)));
typedef float f32x4 __attribute__((ext_vector_type(4)));

__device__ __forceinline__ unsigned short f2b(float f) {
    union { float f; unsigned u; } cv; cv.f = f;
    unsigned u = cv.u;
    unsigned r = (u + 0x7FFFu + ((u >> 16) & 1u)) >> 16;  // RNE
    return (unsigned short)r;
}

__device__ __forceinline__ void gload16(const void* g, void* l) {
    __builtin_amdgcn_global_load_lds(
        (const __attribute__((address_space(1))) unsigned int*)g,
        (__attribute__((address_space(3))) unsigned int*)l, 16, 0, 0);
}

// ---------------- conversion: f32 -> bf16 (vectorized) ----------------
__global__ __launch_bounds__(256) void convert_bf16_kernel(
    const float* __restrict__ in, unsigned short* __restrict__ out, int n4) {
    int i = blockIdx.x * 256 + threadIdx.x;
    if (i < n4) {
        float4 v = reinterpret_cast<const float4*>(in)[i];
        ushort4 o;
        o.x = f2b(v.x); o.y = f2b(v.y); o.z = f2b(v.z); o.w = f2b(v.w);
        reinterpret_cast<ushort4*>(out)[i] = o;
    }
}

// ---------------- transpose + convert: W[R][C] f32 -> Wt[C][R] bf16 ----------------
__global__ __launch_bounds__(256) void transpose_bf16_kernel(
    const float* __restrict__ in, unsigned short* __restrict__ out, int R, int C) {
    __shared__ float tile[32][33];
    int c0 = blockIdx.x * 32, r0 = blockIdx.y * 32;
    int tx = threadIdx.x & 31, ty = threadIdx.x >> 5;  // 32 x 8
    #pragma unroll
    for (int i = ty; i < 32; i += 8)
        tile[i][tx] = in[(size_t)(r0 + i) * C + c0 + tx];
    __syncthreads();
    #pragma unroll
    for (int i = ty; i < 32; i += 8)
        out[(size_t)(c0 + i) * R + r0 + tx] = f2b(tile[tx][i]);
}

// ============ m97-structure GEMM: 128x128 tile, BK=64, global_load_lds staging ============
#define GEMM_STAGE(kt)                                                                   \
    {                                                                                    \
        const char* ga = (const char*)(A + (size_t)bm * K + ((kt) << 6));                \
        const char* gb = (const char*)(Bt + (size_t)bn * K + ((kt) << 6));               \
        const size_t K2 = (size_t)K * 2;                                                 \
        _Pragma("unroll")                                                                \
        for (int p = 0; p < 4; ++p)                                                      \
            gload16(ga + (size_t)(srow + p * 32) * K2 + scol,                            \
                    (char*)As + p * 4096 + t * 16);                                      \
        _Pragma("unroll")                                                                \
        for (int p = 0; p < 4; ++p)                                                      \
            gload16(gb + (size_t)(srow + p * 32) * K2 + scol,                            \
                    (char*)Bs + p * 4096 + t * 16);                                      \
    }

#define GEMM_COMPUTE()                                                                   \
    _Pragma("unroll")                                                                    \
    for (int ks = 0; ks < 64; ks += 32) {                                                \
        bf16x8 af[4], bfv[4];                                                            \
        _Pragma("unroll")                                                                \
        for (int i = 0; i < 4; ++i)                                                      \
            af[i] = *reinterpret_cast<const bf16x8*>(&As[(wrow * 64 + i * 16 + lr) * 64 + ks + lk8]); \
        _Pragma("unroll")                                                                \
        for (int j = 0; j < 4; ++j)                                                      \
            bfv[j] = *reinterpret_cast<const bf16x8*>(&Bs[(wcol * 64 + j * 16 + lr) * 64 + ks + lk8]); \
        _Pragma("unroll")                                                                \
        for (int i = 0; i < 4; ++i)                                                      \
            _Pragma("unroll")                                                            \
            for (int j = 0; j < 4; ++j)                                                  \
                acc[i][j] = __builtin_amdgcn_mfma_f32_16x16x32_bf16(af[i], bfv[j], acc[i][j], 0, 0, 0); \
    }

#define GEMM_PROLOG()                                                                    \
    __shared__ __align__(16) unsigned short As[128 * 64];                                \
    __shared__ __align__(16) unsigned short Bs[128 * 64];                                \
    const int t = threadIdx.x;                                                           \
    const int wave = t >> 6, lane = t & 63;                                              \
    const int wrow = wave >> 1, wcol = wave & 1;                                         \
    const int bn = blockIdx.x * 128, bm = blockIdx.y * 128;                              \
    const int lr = lane & 15;                                                            \
    const int lk8 = (lane >> 4) << 3;                                                    \
    const int srow = t >> 3;                                                             \
    const int scol = (t & 7) * 16;                                                       \
    f32x4 acc[4][4];                                                                     \
    _Pragma("unroll")                                                                    \
    for (int i = 0; i < 4; ++i)                                                          \
        _Pragma("unroll")                                                                \
        for (int j = 0; j < 4; ++j) { f32x4 z = {0.f, 0.f, 0.f, 0.f}; acc[i][j] = z; }   \
    const int nkt = K >> 6;                                                              \
    for (int kt = 0; kt < nkt; ++kt) {                                                   \
        GEMM_STAGE(kt)                                                                   \
        __syncthreads();                                                                 \
        GEMM_COMPUTE()                                                                   \
        __syncthreads();                                                                 \
    }                                                                                    \
    const int r0 = (lane >> 4) << 2;

template <int RELU, int RES, int EF32, int EB16>
__global__ __launch_bounds__(256) void gemm128(
    const unsigned short* __restrict__ A, const unsigned short* __restrict__ Bt,
    const float* __restrict__ bias, const float* __restrict__ res,
    float* __restrict__ outf, unsigned short* __restrict__ outb,
    int M, int N, int K) {
    GEMM_PROLOG()
    #pragma unroll
    for (int i = 0; i < 4; ++i) {
        const int row_b = bm + wrow * 64 + i * 16 + r0;
        #pragma unroll
        for (int j = 0; j < 4; ++j) {
            const int col = bn + wcol * 64 + j * 16 + lr;
            const float bvv = bias[col];
            #pragma unroll
            for (int r = 0; r < 4; ++r) {
                float vv = acc[i][j][r] + bvv;
                if (RES) vv += res[(size_t)(row_b + r) * N + col];
                if (RELU) vv = vv > 0.f ? vv : 0.f;
                if (EF32) outf[(size_t)(row_b + r) * N + col] = vv;
                if (EB16) outb[(size_t)(row_b + r) * N + col] = f2b(vv);
            }
        }
    }
}

// ============ BM=128 x BN=64 variant for N=768 GEMMs (grid fill) ============
template <int RELU, int RES, int EF32, int EB16>
__global__ __launch_bounds__(256) void gemm_bt64(
    const unsigned short* __restrict__ A, const unsigned short* __restrict__ Bt,
    const float* __restrict__ bias, const float* __restrict__ res,
    float* __restrict__ outf, unsigned short* __restrict__ outb,
    int M, int N, int K) {
    __shared__ __align__(16) unsigned short As[128 * 64];
    __shared__ __align__(16) unsigned short Bs[64 * 64];
    const int t = threadIdx.x;
    const int wave = t >> 6, lane = t & 63;
    const int bn = blockIdx.x * 64, bm = blockIdx.y * 128;
    const int lr = lane & 15;
    const int lk8 = (lane >> 4) << 3;
    const int srow = t >> 3;
    const int scol = (t & 7) * 16;
    f32x4 acc[2][4];
    #pragma unroll
    for (int i = 0; i < 2; ++i)
        #pragma unroll
        for (int j = 0; j < 4; ++j) { f32x4 z = {0.f, 0.f, 0.f, 0.f}; acc[i][j] = z; }
    const int nkt = K >> 6;
    for (int kt = 0; kt < nkt; ++kt) {
        const char* ga = (const char*)(A + (size_t)bm * K + (kt << 6));
        const char* gb = (const char*)(Bt + (size_t)bn * K + (kt << 6));
        const size_t K2 = (size_t)K * 2;
        #pragma unroll
        for (int p = 0; p < 4; ++p)
            gload16(ga + (size_t)(srow + p * 32) * K2 + scol, (char*)As + p * 4096 + t * 16);
        #pragma unroll
        for (int p = 0; p < 2; ++p)
            gload16(gb + (size_t)(srow + p * 32) * K2 + scol, (char*)Bs + p * 4096 + t * 16);
        __syncthreads();
        #pragma unroll
        for (int ks = 0; ks < 64; ks += 32) {
            bf16x8 af[2], bfv[4];
            #pragma unroll
            for (int i = 0; i < 2; ++i)
                af[i] = *reinterpret_cast<const bf16x8*>(&As[(wave * 32 + i * 16 + lr) * 64 + ks + lk8]);
            #pragma unroll
            for (int j = 0; j < 4; ++j)
                bfv[j] = *reinterpret_cast<const bf16x8*>(&Bs[(j * 16 + lr) * 64 + ks + lk8]);
            #pragma unroll
            for (int i = 0; i < 2; ++i)
                #pragma unroll
                for (int j = 0; j < 4; ++j)
                    acc[i][j] = __builtin_amdgcn_mfma_f32_16x16x32_bf16(af[i], bfv[j], acc[i][j], 0, 0, 0);
        }
        __syncthreads();
    }
    const int r0 = (lane >> 4) << 2;
    #pragma unroll
    for (int i = 0; i < 2; ++i) {
        const int row_b = bm + wave * 32 + i * 16 + r0;
        #pragma unroll
        for (int j = 0; j < 4; ++j) {
            const int col = bn + j * 16 + lr;
            const float bvv = bias[col];
            #pragma unroll
            for (int r = 0; r < 4; ++r) {
                float vv = acc[i][j][r] + bvv;
                if (RES) vv += res[(size_t)(row_b + r) * N + col];
                if (RELU) vv = vv > 0.f ? vv : 0.f;
                if (EF32) outf[(size_t)(row_b + r) * N + col] = vv;
                if (EB16) outb[(size_t)(row_b + r) * N + col] = f2b(vv);
            }
        }
    }
}

// fused QKV epilogue: N=2304 = [Q | K | V]; Q scaled, K plain -> [B,H,S,64]; V -> [B,H,64,S]
__global__ __launch_bounds__(256) void gemm128_qkv(
    const unsigned short* __restrict__ A, const unsigned short* __restrict__ Bt,
    const float* __restrict__ bq, const float* __restrict__ bk, const float* __restrict__ bv,
    unsigned short* __restrict__ q16, unsigned short* __restrict__ k16,
    unsigned short* __restrict__ vt16, int M, int N, int K, float qscale) {
    GEMM_PROLOG()
    #pragma unroll
    for (int i = 0; i < 4; ++i) {
        const int row_b = bm + wrow * 64 + i * 16 + r0;
        const int b = row_b >> 11, s = row_b & 2047;
        #pragma unroll
        for (int j = 0; j < 4; ++j) {
            const int col = bn + wcol * 64 + j * 16 + lr;
            const int sec = (col >= 2 * DM) ? 2 : (col >= DM ? 1 : 0);
            const int nc = col - sec * DM;
            const int h = nc >> 6, d = nc & 63;
            const float bvv = (sec == 0 ? bq : (sec == 1 ? bk : bv))[nc];
            if (sec == 2) {
                ushort4 w;
                w.x = f2b(acc[i][j][0] + bvv);
                w.y = f2b(acc[i][j][1] + bvv);
                w.z = f2b(acc[i][j][2] + bvv);
                w.w = f2b(acc[i][j][3] + bvv);
                *reinterpret_cast<ushort4*>(
                    vt16 + (((size_t)(b * NH + h) * DKH) + d) * S_LEN + s) = w;
            } else {
                const float sc = (sec == 0) ? qscale : 1.f;
                unsigned short* dst = (sec == 0) ? q16 : k16;
                #pragma unroll
                for (int r = 0; r < 4; ++r)
                    dst[(((size_t)(b * NH + h) * S_LEN) + s + r) * DKH + d] =
                        f2b((acc[i][j][r] + bvv) * sc);
            }
        }
    }
}

// ---------------- MFMA causal flash attention: 16 q-rows/wave, no barriers ----------------
// Grid: x = head (L2 locality), y = q-block-64 (reversed -> heavy first).
// 4 waves/block, each wave owns 16 q-rows independently. K/V read directly from
// global (L2-resident). K+V fragments batch-loaded to regs at iter top so V latency
// hides under QK+softmax. VGPR capped <=128 via launch_bounds -> grid is the binder.
__global__ __launch_bounds__(256, 4) void attn_mfma_kernel(
    const unsigned short* __restrict__ q16,   // [B,H,S,64]
    const unsigned short* __restrict__ k16,   // [B,H,S,64]
    const unsigned short* __restrict__ vt16,  // [B,H,64,S]
    unsigned short* __restrict__ ctx16) {     // [B,S,DM]
    __shared__ __align__(16) unsigned short Pl[4][16][72];  // [wave][q=lr][key]
    const int t = threadIdx.x, wave = t >> 6, lane = t & 63;
    const int bh = blockIdx.x;
    const int qb = (gridDim.y - 1) - blockIdx.y;  // heavy blocks dispatched first
    const int b = bh / NH, h = bh % NH;
    const size_t hbase = (size_t)bh * S_LEN * DKH;
    const int lr = lane & 15;
    const int g4 = (lane >> 4) << 2;
    const int lk8 = (lane >> 4) << 3;
    const int sW = (qb << 6) + wave * 16;  // this wave's first q row

    // Q fragments in registers (pre-scaled to exp2 domain by the QKV GEMM)
    bf16x8 qa[2];
    #pragma unroll
    for (int ks = 0; ks < 2; ++ks)
        qa[ks] = *reinterpret_cast<const bf16x8*>(
            q16 + hbase + (size_t)(sW + lr) * DKH + ks * 32 + lk8);

    float mst = -3e38f, lst = 0.f;
    f32x4 acc[4];
    #pragma unroll
    for (int j = 0; j < 4; ++j) { f32x4 z = {0.f, 0.f, 0.f, 0.f}; acc[j] = z; }

    const unsigned short* kb = k16 + hbase;
    const unsigned short* vbg = vt16 + hbase;
    const int nt = qb + 1;
    for (int kt = 0; kt < nt; ++kt) {
        const int k0 = kt << 6;

        // batch-load K and V fragments (V issued early: latency hides under QK+softmax)
        bf16x8 kr[2][4], vr[2][4];
        #pragma unroll
        for (int ks = 0; ks < 2; ++ks)
            #pragma unroll
            for (int j = 0; j < 4; ++j)
                kr[ks][j] = *reinterpret_cast<const bf16x8*>(
                    kb + (size_t)(k0 + j * 16 + lr) * DKH + ks * 32 + lk8);
        #pragma unroll
        for (int c = 0; c < 2; ++c)
            #pragma unroll
            for (int j = 0; j < 4; ++j)
                vr[c][j] = *reinterpret_cast<const bf16x8*>(
                    vbg + (size_t)(j * 16 + lr) * S_LEN + k0 + c * 32 + lk8);

        // S^T = K * Q^T
        f32x4 sc[4];
        #pragma unroll
        for (int j = 0; j < 4; ++j) { f32x4 z = {0.f, 0.f, 0.f, 0.f}; sc[j] = z; }
        __builtin_amdgcn_s_setprio(1);
        #pragma unroll
        for (int ks = 0; ks < 2; ++ks)
            #pragma unroll
            for (int j = 0; j < 4; ++j)
                sc[j] = __builtin_amdgcn_mfma_f32_16x16x32_bf16(kr[ks][j], qa[ks], sc[j], 0, 0, 0);
        __builtin_amdgcn_s_setprio(0);

        // causal mask: only the last tile crosses the diagonal
        const int qg = sW + lr;
        if (kt == nt - 1) {
            #pragma unroll
            for (int j = 0; j < 4; ++j)
                #pragma unroll
                for (int r = 0; r < 4; ++r)
                    if (k0 + j * 16 + g4 + r > qg) sc[j][r] = -3e38f;
        }

        // online softmax (exp2 domain); lane owns row q = sW + lr
        float m01 = fmaxf(fmaxf(sc[0][0], sc[0][1]), fmaxf(sc[0][2], sc[0][3]));
        float m11 = fmaxf(fmaxf(sc[1][0], sc[1][1]), fmaxf(sc[1][2], sc[1][3]));
        float m21 = fmaxf(fmaxf(sc[2][0], sc[2][1]), fmaxf(sc[2][2], sc[2][3]));
        float m31 = fmaxf(fmaxf(sc[3][0], sc[3][1]), fmaxf(sc[3][2], sc[3][3]));
        float tm = fmaxf(fmaxf(m01, m11), fmaxf(m21, m31));
        tm = fmaxf(tm, __shfl_xor(tm, 16));
        tm = fmaxf(tm, __shfl_xor(tm, 32));
        const float mn = fmaxf(mst, tm);
        const float corr = exp2f(mst - mn);
        float ts = 0.f;
        #pragma unroll
        for (int j = 0; j < 4; ++j)
            #pragma unroll
            for (int r = 0; r < 4; ++r) {
                const float p = exp2f(sc[j][r] - mn);
                sc[j][r] = p;
                ts += p;
            }
        ts += __shfl_xor(ts, 16);
        ts += __shfl_xor(ts, 32);
        lst = lst * corr + ts;
        mst = mn;
        #pragma unroll
        for (int r = 0; r < 4; ++r) {
            const float cr = __shfl(corr, g4 + r);
            #pragma unroll
            for (int j = 0; j < 4; ++j) acc[j][r] *= cr;
        }
        // pack P -> per-wave LDS [q=lr][key]
        #pragma unroll
        for (int j = 0; j < 4; ++j) {
            ushort4 w;
            w.x = f2b(sc[j][0]); w.y = f2b(sc[j][1]);
            w.z = f2b(sc[j][2]); w.w = f2b(sc[j][3]);
            *reinterpret_cast<ushort4*>(&Pl[wave][lr][j * 16 + g4]) = w;
        }

        // PV: out[q][d] += P[q][key] * Vt[d][key]^T
        __builtin_amdgcn_s_setprio(1);
        #pragma unroll
        for (int c = 0; c < 2; ++c) {
            bf16x8 pa = *reinterpret_cast<const bf16x8*>(&Pl[wave][lr][c * 32 + lk8]);
            #pragma unroll
            for (int j = 0; j < 4; ++j)
                acc[j] = __builtin_amdgcn_mfma_f32_16x16x32_bf16(pa, vr[c][j], acc[j], 0, 0, 0);
        }
        __builtin_amdgcn_s_setprio(0);
    }

    const float li = 1.f / lst;
    #pragma unroll
    for (int r = 0; r < 4; ++r) {
        const float lrc = __shfl(li, g4 + r);
        const int srow = sW + g4 + r;
        #pragma unroll
        for (int j = 0; j < 4; ++j) {
            ctx16[((size_t)b * S_LEN + srow) * DM + h * DKH + j * 16 + lr] =
                f2b(acc[j][r] * lrc);
        }
    }
}

// ---------------- row LayerNorm, optional bf16 copy ----------------
template <int EB16>
__global__ __launch_bounds__(256) void layernorm_kernel(
    const float* __restrict__ in, const float* __restrict__ gam, const float* __restrict__ bet,
    float* __restrict__ outf, unsigned short* __restrict__ outb) {
    __shared__ float red[8];
    const int row = blockIdx.x, t = threadIdx.x;
    const int wave = t >> 6, lane = t & 63;
    const float* p = in + (size_t)row * DM;
    const float v0 = p[t], v1 = p[t + 256], v2 = p[t + 512];
    float s = v0 + v1 + v2;
    float sq = v0 * v0 + v1 * v1 + v2 * v2;
    #pragma unroll
    for (int off = 32; off > 0; off >>= 1) { s += __shfl_xor(s, off); sq += __shfl_xor(sq, off); }
    if (lane == 0) { red[wave] = s; red[wave + 4] = sq; }
    __syncthreads();
    s = red[0] + red[1] + red[2] + red[3];
    sq = red[4] + red[5] + red[6] + red[7];
    const float mu = s * (1.f / DM);
    const float var = sq * (1.f / DM) - mu * mu;
    const float rs = rsqrtf(var + 1e-5f);
    #pragma unroll
    for (int i = 0; i < 3; ++i) {
        const int c = t + i * 256;
        const float vv = (i == 0 ? v0 : (i == 1 ? v1 : v2));
        const float y = (vv - mu) * rs * gam[c] + bet[c];
        outf[(size_t)row * DM + c] = y;
        if (EB16) outb[(size_t)row * DM + c] = f2b(y);
    }
}

extern "C" void kernel_launch(void* const* d_in, const int* in_sizes, int n_in,
                              void* d_out, int out_size, void* d_ws, size_t ws_size,
                              hipStream_t stream) {
    const float* x   = (const float*)d_in[0];
    const float* wq  = (const float*)d_in[1];
    const float* bq  = (const float*)d_in[2];
    const float* wk  = (const float*)d_in[3];
    const float* bk  = (const float*)d_in[4];
    const float* wv  = (const float*)d_in[5];
    const float* bv  = (const float*)d_in[6];
    const float* wo  = (const float*)d_in[7];
    const float* bo  = (const float*)d_in[8];
    const float* w1  = (const float*)d_in[9];
    const float* b1  = (const float*)d_in[10];
    const float* w2  = (const float*)d_in[11];
    const float* b2  = (const float*)d_in[12];
    const float* g1  = (const float*)d_in[13];
    const float* be1 = (const float*)d_in[14];
    const float* g2  = (const float*)d_in[15];
    const float* be2 = (const float*)d_in[16];

    char* wp = (char*)d_ws;
    auto alloc = [&](size_t bytes) -> void* {
        void* r = (void*)wp;
        wp += (bytes + 255) & ~(size_t)255;
        return r;
    };
    const int M = MROWS;
    unsigned short* wqkv16 = (unsigned short*)alloc((size_t)3 * DM * DM * 2);  // [2304][768]
    unsigned short* wo16 = (unsigned short*)alloc((size_t)DM * DM * 2);
    unsigned short* w116 = (unsigned short*)alloc((size_t)DM * DFF * 2);
    unsigned short* w216 = (unsigned short*)alloc((size_t)DM * DFF * 2);
    unsigned short* ctx16 = (unsigned short*)alloc((size_t)M * DM * 2);
    float* y1 = (float*)alloc((size_t)M * DM * 4);
    unsigned short* x16  = (unsigned short*)alloc((size_t)M * DM * 2);
    unsigned short* q16  = (unsigned short*)alloc((size_t)M * DM * 2);
    unsigned short* k16  = (unsigned short*)alloc((size_t)M * DM * 2);
    unsigned short* vt16 = (unsigned short*)alloc((size_t)M * DM * 2);
    unsigned short* ff116 = x16;    // [M,DFF] bf16 over x16..vt16 (contiguous, dead after QKV/attn)
    unsigned short* x116  = ctx16;  // LN1 bf16 output

    convert_bf16_kernel<<<(M * DM / 4 + 255) / 256, 256, 0, stream>>>(x, x16, M * DM / 4);
    transpose_bf16_kernel<<<dim3(DM / 32, DM / 32), 256, 0, stream>>>(wq, wqkv16, DM, DM);
    transpose_bf16_kernel<<<dim3(DM / 32, DM / 32), 256, 0, stream>>>(wk, wqkv16 + (size_t)DM * DM, DM, DM);
    transpose_bf16_kernel<<<dim3(DM / 32, DM / 32), 256, 0, stream>>>(wv, wqkv16 + (size_t)2 * DM * DM, DM, DM);
    transpose_bf16_kernel<<<dim3(DM / 32, DM / 32), 256, 0, stream>>>(wo, wo16, DM, DM);
    transpose_bf16_kernel<<<dim3(DFF / 32, DM / 32), 256, 0, stream>>>(w1, w116, DM, DFF);
    transpose_bf16_kernel<<<dim3(DM / 32, DFF / 32), 256, 0, stream>>>(w2, w216, DFF, DM);

    const float QSCALE = 0.125f * 1.44269504088896f;
    gemm128_qkv<<<dim3(3 * DM / 128, M / 128), 256, 0, stream>>>(
        x16, wqkv16, bq, bk, bv, q16, k16, vt16, M, 3 * DM, DM, QSCALE);

    attn_mfma_kernel<<<dim3(BATCH * NH, S_LEN / 64), 256, 0, stream>>>(q16, k16, vt16, ctx16);

    gemm_bt64<0, 1, 1, 0><<<dim3(DM / 64, M / 128), 256, 0, stream>>>(
        ctx16, wo16, bo, x, y1, nullptr, M, DM, DM);
    layernorm_kernel<1><<<M, 256, 0, stream>>>(y1, g1, be1, y1, x116);

    gemm128<1, 0, 0, 1><<<dim3(DFF / 128, M / 128), 256, 0, stream>>>(
        x116, w116, b1, nullptr, nullptr, ff116, M, DFF, DM);
    gemm_bt64<0, 1, 1, 0><<<dim3(DM / 64, M / 128), 256, 0, stream>>>(
        ff116, w216, b2, y1, (float*)d_out, nullptr, M, DM, DFF);
    layernorm_kernel<0><<<M, 256, 0, stream>>>((float*)d_out, g2, be2, (float*)d_out, nullptr);
}

// Round 7
// 260.491 us; speedup vs baseline: 1.2179x; 1.2179x over previous
//
#include <hip/hip_runtime.h>
#include <stdint.h>

#define S_LEN 2048
#define BATCH 2
#define DM 768
#define NH 12
#define DKH 64
#define DFF 3072
#define MROWS (BATCH * S_LEN)  // 4096

typedef short bf16x8 __attribute__((ext_vector_type(8)));
typedef float f32x4 __attribute__((ext_vector_type(4)));
typedef float f32x16 __attribute__((ext_vector_type(16)));

__device__ __forceinline__ unsigned short f2b(float f) {
    union { float f; unsigned u; } cv; cv.f = f;
    unsigned u = cv.u;
    unsigned r = (u + 0x7FFFu + ((u >> 16) & 1u)) >> 16;  // RNE
    return (unsigned short)r;
}

__device__ __forceinline__ void gload16(const void* g, void* l) {
    __builtin_amdgcn_global_load_lds(
        (const __attribute__((address_space(1))) unsigned int*)g,
        (__attribute__((address_space(3))) unsigned int*)l, 16, 0, 0);
}

__device__ __forceinline__ unsigned cvtpk(float lo, float hi) {
    unsigned r;
    asm("v_cvt_pk_bf16_f32 %0, %1, %2" : "=v"(r) : "v"(lo), "v"(hi));
    return r;
}
__device__ __forceinline__ void pswap(unsigned &a, unsigned &b) {
    asm("v_permlane32_swap_b32 %0, %1" : "+v"(a), "+v"(b));
}
__device__ __forceinline__ bf16x8 mkpa(unsigned w0, unsigned w1, unsigned w2, unsigned w3) {
    union { unsigned u[4]; bf16x8 h; } cv;
    cv.u[0] = w0; cv.u[1] = w1; cv.u[2] = w2; cv.u[3] = w3;
    return cv.h;
}

// ---------------- conversion: f32 -> bf16 (vectorized) ----------------
__global__ __launch_bounds__(256) void convert_bf16_kernel(
    const float* __restrict__ in, unsigned short* __restrict__ out, int n4) {
    int i = blockIdx.x * 256 + threadIdx.x;
    if (i < n4) {
        float4 v = reinterpret_cast<const float4*>(in)[i];
        ushort4 o;
        o.x = f2b(v.x); o.y = f2b(v.y); o.z = f2b(v.z); o.w = f2b(v.w);
        reinterpret_cast<ushort4*>(out)[i] = o;
    }
}

// ---------------- transpose + convert: W[R][C] f32 -> Wt[C][R] bf16 ----------------
__global__ __launch_bounds__(256) void transpose_bf16_kernel(
    const float* __restrict__ in, unsigned short* __restrict__ out, int R, int C) {
    __shared__ float tile[32][33];
    int c0 = blockIdx.x * 32, r0 = blockIdx.y * 32;
    int tx = threadIdx.x & 31, ty = threadIdx.x >> 5;  // 32 x 8
    #pragma unroll
    for (int i = ty; i < 32; i += 8)
        tile[i][tx] = in[(size_t)(r0 + i) * C + c0 + tx];
    __syncthreads();
    #pragma unroll
    for (int i = ty; i < 32; i += 8)
        out[(size_t)(c0 + i) * R + r0 + tx] = f2b(tile[tx][i]);
}

// ============ m97-structure GEMM: 128x128 tile, BK=64, global_load_lds staging ============
#define GEMM_STAGE(kt)                                                                   \
    {                                                                                    \
        const char* ga = (const char*)(A + (size_t)bm * K + ((kt) << 6));                \
        const char* gb = (const char*)(Bt + (size_t)bn * K + ((kt) << 6));               \
        const size_t K2 = (size_t)K * 2;                                                 \
        _Pragma("unroll")                                                                \
        for (int p = 0; p < 4; ++p)                                                      \
            gload16(ga + (size_t)(srow + p * 32) * K2 + scol,                            \
                    (char*)As + p * 4096 + t * 16);                                      \
        _Pragma("unroll")                                                                \
        for (int p = 0; p < 4; ++p)                                                      \
            gload16(gb + (size_t)(srow + p * 32) * K2 + scol,                            \
                    (char*)Bs + p * 4096 + t * 16);                                      \
    }

#define GEMM_COMPUTE()                                                                   \
    _Pragma("unroll")                                                                    \
    for (int ks = 0; ks < 64; ks += 32) {                                                \
        bf16x8 af[4], bfv[4];                                                            \
        _Pragma("unroll")                                                                \
        for (int i = 0; i < 4; ++i)                                                      \
            af[i] = *reinterpret_cast<const bf16x8*>(&As[(wrow * 64 + i * 16 + lr) * 64 + ks + lk8]); \
        _Pragma("unroll")                                                                \
        for (int j = 0; j < 4; ++j)                                                      \
            bfv[j] = *reinterpret_cast<const bf16x8*>(&Bs[(wcol * 64 + j * 16 + lr) * 64 + ks + lk8]); \
        _Pragma("unroll")                                                                \
        for (int i = 0; i < 4; ++i)                                                      \
            _Pragma("unroll")                                                            \
            for (int j = 0; j < 4; ++j)                                                  \
                acc[i][j] = __builtin_amdgcn_mfma_f32_16x16x32_bf16(af[i], bfv[j], acc[i][j], 0, 0, 0); \
    }

#define GEMM_PROLOG()                                                                    \
    __shared__ __align__(16) unsigned short As[128 * 64];                                \
    __shared__ __align__(16) unsigned short Bs[128 * 64];                                \
    const int t = threadIdx.x;                                                           \
    const int wave = t >> 6, lane = t & 63;                                              \
    const int wrow = wave >> 1, wcol = wave & 1;                                         \
    const int bn = blockIdx.x * 128, bm = blockIdx.y * 128;                              \
    const int lr = lane & 15;                                                            \
    const int lk8 = (lane >> 4) << 3;                                                    \
    const int srow = t >> 3;                                                             \
    const int scol = (t & 7) * 16;                                                       \
    f32x4 acc[4][4];                                                                     \
    _Pragma("unroll")                                                                    \
    for (int i = 0; i < 4; ++i)                                                          \
        _Pragma("unroll")                                                                \
        for (int j = 0; j < 4; ++j) { f32x4 z = {0.f, 0.f, 0.f, 0.f}; acc[i][j] = z; }   \
    const int nkt = K >> 6;                                                              \
    for (int kt = 0; kt < nkt; ++kt) {                                                   \
        GEMM_STAGE(kt)                                                                   \
        __syncthreads();                                                                 \
        GEMM_COMPUTE()                                                                   \
        __syncthreads();                                                                 \
    }                                                                                    \
    const int r0 = (lane >> 4) << 2;

template <int RELU, int RES, int EF32, int EB16>
__global__ __launch_bounds__(256) void gemm128(
    const unsigned short* __restrict__ A, const unsigned short* __restrict__ Bt,
    const float* __restrict__ bias, const float* __restrict__ res,
    float* __restrict__ outf, unsigned short* __restrict__ outb,
    int M, int N, int K) {
    GEMM_PROLOG()
    #pragma unroll
    for (int i = 0; i < 4; ++i) {
        const int row_b = bm + wrow * 64 + i * 16 + r0;
        #pragma unroll
        for (int j = 0; j < 4; ++j) {
            const int col = bn + wcol * 64 + j * 16 + lr;
            const float bvv = bias[col];
            #pragma unroll
            for (int r = 0; r < 4; ++r) {
                float vv = acc[i][j][r] + bvv;
                if (RES) vv += res[(size_t)(row_b + r) * N + col];
                if (RELU) vv = vv > 0.f ? vv : 0.f;
                if (EF32) outf[(size_t)(row_b + r) * N + col] = vv;
                if (EB16) outb[(size_t)(row_b + r) * N + col] = f2b(vv);
            }
        }
    }
}

// ============ BM=128 x BN=64 variant for N=768 GEMMs (grid fill) ============
template <int RELU, int RES, int EF32, int EB16>
__global__ __launch_bounds__(256) void gemm_bt64(
    const unsigned short* __restrict__ A, const unsigned short* __restrict__ Bt,
    const float* __restrict__ bias, const float* __restrict__ res,
    float* __restrict__ outf, unsigned short* __restrict__ outb,
    int M, int N, int K) {
    __shared__ __align__(16) unsigned short As[128 * 64];
    __shared__ __align__(16) unsigned short Bs[64 * 64];
    const int t = threadIdx.x;
    const int wave = t >> 6, lane = t & 63;
    const int bn = blockIdx.x * 64, bm = blockIdx.y * 128;
    const int lr = lane & 15;
    const int lk8 = (lane >> 4) << 3;
    const int srow = t >> 3;
    const int scol = (t & 7) * 16;
    f32x4 acc[2][4];
    #pragma unroll
    for (int i = 0; i < 2; ++i)
        #pragma unroll
        for (int j = 0; j < 4; ++j) { f32x4 z = {0.f, 0.f, 0.f, 0.f}; acc[i][j] = z; }
    const int nkt = K >> 6;
    for (int kt = 0; kt < nkt; ++kt) {
        const char* ga = (const char*)(A + (size_t)bm * K + (kt << 6));
        const char* gb = (const char*)(Bt + (size_t)bn * K + (kt << 6));
        const size_t K2 = (size_t)K * 2;
        #pragma unroll
        for (int p = 0; p < 4; ++p)
            gload16(ga + (size_t)(srow + p * 32) * K2 + scol, (char*)As + p * 4096 + t * 16);
        #pragma unroll
        for (int p = 0; p < 2; ++p)
            gload16(gb + (size_t)(srow + p * 32) * K2 + scol, (char*)Bs + p * 4096 + t * 16);
        __syncthreads();
        #pragma unroll
        for (int ks = 0; ks < 64; ks += 32) {
            bf16x8 af[2], bfv[4];
            #pragma unroll
            for (int i = 0; i < 2; ++i)
                af[i] = *reinterpret_cast<const bf16x8*>(&As[(wave * 32 + i * 16 + lr) * 64 + ks + lk8]);
            #pragma unroll
            for (int j = 0; j < 4; ++j)
                bfv[j] = *reinterpret_cast<const bf16x8*>(&Bs[(j * 16 + lr) * 64 + ks + lk8]);
            #pragma unroll
            for (int i = 0; i < 2; ++i)
                #pragma unroll
                for (int j = 0; j < 4; ++j)
                    acc[i][j] = __builtin_amdgcn_mfma_f32_16x16x32_bf16(af[i], bfv[j], acc[i][j], 0, 0, 0);
        }
        __syncthreads();
    }
    const int r0 = (lane >> 4) << 2;
    #pragma unroll
    for (int i = 0; i < 2; ++i) {
        const int row_b = bm + wave * 32 + i * 16 + r0;
        #pragma unroll
        for (int j = 0; j < 4; ++j) {
            const int col = bn + j * 16 + lr;
            const float bvv = bias[col];
            #pragma unroll
            for (int r = 0; r < 4; ++r) {
                float vv = acc[i][j][r] + bvv;
                if (RES) vv += res[(size_t)(row_b + r) * N + col];
                if (RELU) vv = vv > 0.f ? vv : 0.f;
                if (EF32) outf[(size_t)(row_b + r) * N + col] = vv;
                if (EB16) outb[(size_t)(row_b + r) * N + col] = f2b(vv);
            }
        }
    }
}

// fused QKV epilogue: N=2304 = [Q | K | V]; Q scaled, K plain -> [B,H,S,64]; V -> [B,H,64,S]
__global__ __launch_bounds__(256) void gemm128_qkv(
    const unsigned short* __restrict__ A, const unsigned short* __restrict__ Bt,
    const float* __restrict__ bq, const float* __restrict__ bk, const float* __restrict__ bv,
    unsigned short* __restrict__ q16, unsigned short* __restrict__ k16,
    unsigned short* __restrict__ vt16, int M, int N, int K, float qscale) {
    GEMM_PROLOG()
    #pragma unroll
    for (int i = 0; i < 4; ++i) {
        const int row_b = bm + wrow * 64 + i * 16 + r0;
        const int b = row_b >> 11, s = row_b & 2047;
        #pragma unroll
        for (int j = 0; j < 4; ++j) {
            const int col = bn + wcol * 64 + j * 16 + lr;
            const int sec = (col >= 2 * DM) ? 2 : (col >= DM ? 1 : 0);
            const int nc = col - sec * DM;
            const int h = nc >> 6, d = nc & 63;
            const float bvv = (sec == 0 ? bq : (sec == 1 ? bk : bv))[nc];
            if (sec == 2) {
                ushort4 w;
                w.x = f2b(acc[i][j][0] + bvv);
                w.y = f2b(acc[i][j][1] + bvv);
                w.z = f2b(acc[i][j][2] + bvv);
                w.w = f2b(acc[i][j][3] + bvv);
                *reinterpret_cast<ushort4*>(
                    vt16 + (((size_t)(b * NH + h) * DKH) + d) * S_LEN + s) = w;
            } else {
                const float sc = (sec == 0) ? qscale : 1.f;
                unsigned short* dst = (sec == 0) ? q16 : k16;
                #pragma unroll
                for (int r = 0; r < 4; ++r)
                    dst[(((size_t)(b * NH + h) * S_LEN) + s + r) * DKH + d] =
                        f2b((acc[i][j][r] + bvv) * sc);
            }
        }
    }
}

// ---------------- MFMA causal flash attention: 32x32, fully in-register ----------------
// 1 wave/block, 32 q-rows/wave. Swapped QK^T (mfma(K,Q)): lane owns q-row (col=lane&31).
// Softmax in-register: 31 fmax + 1 shfl_xor(32). P -> PV A-frags via cvt_pk_bf16 +
// permlane32_swap (T12) -- NO LDS, NO barriers. Defer-max rescale (T13, THR=8 exp2-dom).
// K/V direct from global (L2-resident). Grid: x=head, y=32-row q-block (heavy first).
__global__ __launch_bounds__(64) void attn_mfma_kernel(
    const unsigned short* __restrict__ q16,   // [B,H,S,64]
    const unsigned short* __restrict__ k16,   // [B,H,S,64]
    const unsigned short* __restrict__ vt16,  // [B,H,64,S]
    unsigned short* __restrict__ ctx16) {     // [B,S,DM]
    const int lane = threadIdx.x & 63;
    const int bh = blockIdx.x;
    const int qb = (gridDim.y - 1) - blockIdx.y;
    const int b = bh / NH, h = bh % NH;
    const size_t hbase = (size_t)bh * S_LEN * DKH;
    const int x = lane & 31;    // q-col (QK) / key-row (K frag) / d-col (PV)
    const int hi = lane >> 5;
    const int k8 = hi << 3;     // k-offset within fragments
    const int sW = qb << 5;     // wave's first q row
    const int qg = sW + x;      // this lane's q row

    // Q fragments (B-operand): Q[sW+x][c*16 + k8 .. +7], pre-scaled to exp2 domain
    bf16x8 qa[4];
    #pragma unroll
    for (int c = 0; c < 4; ++c)
        qa[c] = *reinterpret_cast<const bf16x8*>(
            q16 + hbase + (size_t)(sW + x) * DKH + c * 16 + k8);

    float mst = -3e38f, lst = 0.f;
    f32x16 acc0, acc1;
    #pragma unroll
    for (int r = 0; r < 16; ++r) { acc0[r] = 0.f; acc1[r] = 0.f; }

    const unsigned short* kb = k16 + hbase;
    const unsigned short* vbg = vt16 + hbase;
    const int nt = (sW >> 6) + 1;
    for (int kt = 0; kt < nt; ++kt) {
        const int k0 = kt << 6;

        // V B-frags issued first (latency hides under QK + softmax)
        bf16x8 vb[2][4];
        #pragma unroll
        for (int dt = 0; dt < 2; ++dt)
            #pragma unroll
            for (int s = 0; s < 4; ++s)
                vb[dt][s] = *reinterpret_cast<const bf16x8*>(
                    vbg + (size_t)(dt * 32 + x) * S_LEN + k0 + s * 16 + k8);
        // K A-frags
        bf16x8 ka[2][4];
        #pragma unroll
        for (int kh = 0; kh < 2; ++kh)
            #pragma unroll
            for (int c = 0; c < 4; ++c)
                ka[kh][c] = *reinterpret_cast<const bf16x8*>(
                    kb + (size_t)(k0 + kh * 32 + x) * DKH + c * 16 + k8);

        // S^T = K * Q^T : C[key][q], two key-half tiles
        f32x16 sc0, sc1;
        #pragma unroll
        for (int r = 0; r < 16; ++r) { sc0[r] = 0.f; sc1[r] = 0.f; }
        __builtin_amdgcn_s_setprio(1);
        #pragma unroll
        for (int c = 0; c < 4; ++c) {
            sc0 = __builtin_amdgcn_mfma_f32_32x32x16_bf16(ka[0][c], qa[c], sc0, 0, 0, 0);
            sc1 = __builtin_amdgcn_mfma_f32_32x32x16_bf16(ka[1][c], qa[c], sc1, 0, 0, 0);
        }
        __builtin_amdgcn_s_setprio(0);

        // causal mask (last tile only); key = k0 + (r&3) + 4*hi + 8*(r>>2) (+32 for sc1)
        if (kt == nt - 1) {
            #pragma unroll
            for (int r = 0; r < 16; ++r) {
                const int cr = (r & 3) + (hi << 2) + ((r >> 2) << 3);
                if (k0 + cr > qg) sc0[r] = -3e38f;
                if (k0 + 32 + cr > qg) sc1[r] = -3e38f;
            }
        }

        // row max: 31 in-register fmax + 1 cross-half exchange
        float tm = fmaxf(sc0[0], sc0[1]);
        #pragma unroll
        for (int r = 2; r < 16; ++r) tm = fmaxf(tm, sc0[r]);
        #pragma unroll
        for (int r = 0; r < 16; ++r) tm = fmaxf(tm, sc1[r]);
        tm = fmaxf(tm, __shfl_xor(tm, 32));

        // defer-max (T13): rescale only when some row's max grew past THR=8
        if (!__all(tm <= mst + 8.f)) {
            const float mn = fmaxf(mst, tm);
            const float corr = exp2f(mst - mn);
            mst = mn;
            lst *= corr;
            float cw[16];
            #pragma unroll
            for (int r = 0; r < 16; ++r)
                cw[r] = __shfl(corr, (r & 3) + (hi << 2) + ((r >> 2) << 3));
            #pragma unroll
            for (int r = 0; r < 16; ++r) { acc0[r] *= cw[r]; acc1[r] *= cw[r]; }
        }

        // p = exp2(s - m), row sum
        float ts = 0.f;
        #pragma unroll
        for (int r = 0; r < 16; ++r) {
            sc0[r] = exp2f(sc0[r] - mst); ts += sc0[r];
            sc1[r] = exp2f(sc1[r] - mst); ts += sc1[r];
        }
        ts += __shfl_xor(ts, 32);
        lst += ts;

        // pack P into PV A-fragments in-register (T12: cvt_pk + permlane32_swap)
        unsigned a0 = cvtpk(sc0[0], sc0[1]),   b0 = cvtpk(sc0[4], sc0[5]);   pswap(a0, b0);
        unsigned a1 = cvtpk(sc0[2], sc0[3]),   b1 = cvtpk(sc0[6], sc0[7]);   pswap(a1, b1);
        unsigned a2 = cvtpk(sc0[8], sc0[9]),   b2 = cvtpk(sc0[12], sc0[13]); pswap(a2, b2);
        unsigned a3 = cvtpk(sc0[10], sc0[11]), b3 = cvtpk(sc0[14], sc0[15]); pswap(a3, b3);
        bf16x8 pa00 = mkpa(a0, a1, b0, b1);   // keys [k0,    k0+16)
        bf16x8 pa01 = mkpa(a2, a3, b2, b3);   // keys [k0+16, k0+32)
        unsigned c0 = cvtpk(sc1[0], sc1[1]),   d0 = cvtpk(sc1[4], sc1[5]);   pswap(c0, d0);
        unsigned c1 = cvtpk(sc1[2], sc1[3]),   d1 = cvtpk(sc1[6], sc1[7]);   pswap(c1, d1);
        unsigned c2 = cvtpk(sc1[8], sc1[9]),   d2 = cvtpk(sc1[12], sc1[13]); pswap(c2, d2);
        unsigned c3 = cvtpk(sc1[10], sc1[11]), d3 = cvtpk(sc1[14], sc1[15]); pswap(c3, d3);
        bf16x8 pa10 = mkpa(c0, c1, d0, d1);   // keys [k0+32, k0+48)
        bf16x8 pa11 = mkpa(c2, c3, d2, d3);   // keys [k0+48, k0+64)

        // PV: out[q][d] += P[q][k] * V[k][d]
        __builtin_amdgcn_s_setprio(1);
        acc0 = __builtin_amdgcn_mfma_f32_32x32x16_bf16(pa00, vb[0][0], acc0, 0, 0, 0);
        acc1 = __builtin_amdgcn_mfma_f32_32x32x16_bf16(pa00, vb[1][0], acc1, 0, 0, 0);
        acc0 = __builtin_amdgcn_mfma_f32_32x32x16_bf16(pa01, vb[0][1], acc0, 0, 0, 0);
        acc1 = __builtin_amdgcn_mfma_f32_32x32x16_bf16(pa01, vb[1][1], acc1, 0, 0, 0);
        acc0 = __builtin_amdgcn_mfma_f32_32x32x16_bf16(pa10, vb[0][2], acc0, 0, 0, 0);
        acc1 = __builtin_amdgcn_mfma_f32_32x32x16_bf16(pa10, vb[1][2], acc1, 0, 0, 0);
        acc0 = __builtin_amdgcn_mfma_f32_32x32x16_bf16(pa11, vb[0][3], acc0, 0, 0, 0);
        acc1 = __builtin_amdgcn_mfma_f32_32x32x16_bf16(pa11, vb[1][3], acc1, 0, 0, 0);
        __builtin_amdgcn_s_setprio(0);
    }

    // epilogue: out reg r -> row q = sW + cr(r,hi), col d = dt*32 + x
    const float li = 1.f / lst;
    float lw[16];
    #pragma unroll
    for (int r = 0; r < 16; ++r)
        lw[r] = __shfl(li, (r & 3) + (hi << 2) + ((r >> 2) << 3));
    #pragma unroll
    for (int r = 0; r < 16; ++r) {
        const int q = sW + (r & 3) + (hi << 2) + ((r >> 2) << 3);
        const size_t rowb = ((size_t)b * S_LEN + q) * DM + h * DKH;
        ctx16[rowb + x] = f2b(acc0[r] * lw[r]);
        ctx16[rowb + 32 + x] = f2b(acc1[r] * lw[r]);
    }
}

// ---------------- row LayerNorm, optional bf16 copy ----------------
template <int EB16>
__global__ __launch_bounds__(256) void layernorm_kernel(
    const float* __restrict__ in, const float* __restrict__ gam, const float* __restrict__ bet,
    float* __restrict__ outf, unsigned short* __restrict__ outb) {
    __shared__ float red[8];
    const int row = blockIdx.x, t = threadIdx.x;
    const int wave = t >> 6, lane = t & 63;
    const float* p = in + (size_t)row * DM;
    const float v0 = p[t], v1 = p[t + 256], v2 = p[t + 512];
    float s = v0 + v1 + v2;
    float sq = v0 * v0 + v1 * v1 + v2 * v2;
    #pragma unroll
    for (int off = 32; off > 0; off >>= 1) { s += __shfl_xor(s, off); sq += __shfl_xor(sq, off); }
    if (lane == 0) { red[wave] = s; red[wave + 4] = sq; }
    __syncthreads();
    s = red[0] + red[1] + red[2] + red[3];
    sq = red[4] + red[5] + red[6] + red[7];
    const float mu = s * (1.f / DM);
    const float var = sq * (1.f / DM) - mu * mu;
    const float rs = rsqrtf(var + 1e-5f);
    #pragma unroll
    for (int i = 0; i < 3; ++i) {
        const int c = t + i * 256;
        const float vv = (i == 0 ? v0 : (i == 1 ? v1 : v2));
        const float y = (vv - mu) * rs * gam[c] + bet[c];
        outf[(size_t)row * DM + c] = y;
        if (EB16) outb[(size_t)row * DM + c] = f2b(y);
    }
}

extern "C" void kernel_launch(void* const* d_in, const int* in_sizes, int n_in,
                              void* d_out, int out_size, void* d_ws, size_t ws_size,
                              hipStream_t stream) {
    const float* x   = (const float*)d_in[0];
    const float* wq  = (const float*)d_in[1];
    const float* bq  = (const float*)d_in[2];
    const float* wk  = (const float*)d_in[3];
    const float* bk  = (const float*)d_in[4];
    const float* wv  = (const float*)d_in[5];
    const float* bv  = (const float*)d_in[6];
    const float* wo  = (const float*)d_in[7];
    const float* bo  = (const float*)d_in[8];
    const float* w1  = (const float*)d_in[9];
    const float* b1  = (const float*)d_in[10];
    const float* w2  = (const float*)d_in[11];
    const float* b2  = (const float*)d_in[12];
    const float* g1  = (const float*)d_in[13];
    const float* be1 = (const float*)d_in[14];
    const float* g2  = (const float*)d_in[15];
    const float* be2 = (const float*)d_in[16];

    char* wp = (char*)d_ws;
    auto alloc = [&](size_t bytes) -> void* {
        void* r = (void*)wp;
        wp += (bytes + 255) & ~(size_t)255;
        return r;
    };
    const int M = MROWS;
    unsigned short* wqkv16 = (unsigned short*)alloc((size_t)3 * DM * DM * 2);  // [2304][768]
    unsigned short* wo16 = (unsigned short*)alloc((size_t)DM * DM * 2);
    unsigned short* w116 = (unsigned short*)alloc((size_t)DM * DFF * 2);
    unsigned short* w216 = (unsigned short*)alloc((size_t)DM * DFF * 2);
    unsigned short* ctx16 = (unsigned short*)alloc((size_t)M * DM * 2);
    float* y1 = (float*)alloc((size_t)M * DM * 4);
    unsigned short* x16  = (unsigned short*)alloc((size_t)M * DM * 2);
    unsigned short* q16  = (unsigned short*)alloc((size_t)M * DM * 2);
    unsigned short* k16  = (unsigned short*)alloc((size_t)M * DM * 2);
    unsigned short* vt16 = (unsigned short*)alloc((size_t)M * DM * 2);
    unsigned short* ff116 = x16;    // [M,DFF] bf16 over x16..vt16 (contiguous, dead after QKV/attn)
    unsigned short* x116  = ctx16;  // LN1 bf16 output

    convert_bf16_kernel<<<(M * DM / 4 + 255) / 256, 256, 0, stream>>>(x, x16, M * DM / 4);
    transpose_bf16_kernel<<<dim3(DM / 32, DM / 32), 256, 0, stream>>>(wq, wqkv16, DM, DM);
    transpose_bf16_kernel<<<dim3(DM / 32, DM / 32), 256, 0, stream>>>(wk, wqkv16 + (size_t)DM * DM, DM, DM);
    transpose_bf16_kernel<<<dim3(DM / 32, DM / 32), 256, 0, stream>>>(wv, wqkv16 + (size_t)2 * DM * DM, DM, DM);
    transpose_bf16_kernel<<<dim3(DM / 32, DM / 32), 256, 0, stream>>>(wo, wo16, DM, DM);
    transpose_bf16_kernel<<<dim3(DFF / 32, DM / 32), 256, 0, stream>>>(w1, w116, DM, DFF);
    transpose_bf16_kernel<<<dim3(DM / 32, DFF / 32), 256, 0, stream>>>(w2, w216, DFF, DM);

    const float QSCALE = 0.125f * 1.44269504088896f;
    gemm128_qkv<<<dim3(3 * DM / 128, M / 128), 256, 0, stream>>>(
        x16, wqkv16, bq, bk, bv, q16, k16, vt16, M, 3 * DM, DM, QSCALE);

    attn_mfma_kernel<<<dim3(BATCH * NH, S_LEN / 32), 64, 0, stream>>>(q16, k16, vt16, ctx16);

    gemm_bt64<0, 1, 1, 0><<<dim3(DM / 64, M / 128), 256, 0, stream>>>(
        ctx16, wo16, bo, x, y1, nullptr, M, DM, DM);
    layernorm_kernel<1><<<M, 256, 0, stream>>>(y1, g1, be1, y1, x116);

    gemm128<1, 0, 0, 1><<<dim3(DFF / 128, M / 128), 256, 0, stream>>>(
        x116, w116, b1, nullptr, nullptr, ff116, M, DFF, DM);
    gemm_bt64<0, 1, 1, 0><<<dim3(DM / 64, M / 128), 256, 0, stream>>>(
        ff116, w216, b2, y1, (float*)d_out, nullptr, M, DM, DFF);
    layernorm_kernel<0><<<M, 256, 0, stream>>>((float*)d_out, g2, be2, (float*)d_out, nullptr);
}

// Round 8
// 235.399 us; speedup vs baseline: 1.3477x; 1.1066x over previous
//
#include <hip/hip_runtime.h>
#include <stdint.h>

#define S_LEN 2048
#define BATCH 2
#define DM 768
#define NH 12
#define DKH 64
#define DFF 3072
#define MROWS (BATCH * S_LEN)  // 4096

typedef short bf16x8 __attribute__((ext_vector_type(8)));
typedef float f32x4 __attribute__((ext_vector_type(4)));
typedef float f32x16 __attribute__((ext_vector_type(16)));

__device__ __forceinline__ unsigned short f2b(float f) {
    union { float f; unsigned u; } cv; cv.f = f;
    unsigned u = cv.u;
    unsigned r = (u + 0x7FFFu + ((u >> 16) & 1u)) >> 16;  // RNE
    return (unsigned short)r;
}

__device__ __forceinline__ void gload16(const void* g, void* l) {
    __builtin_amdgcn_global_load_lds(
        (const __attribute__((address_space(1))) unsigned int*)g,
        (__attribute__((address_space(3))) unsigned int*)l, 16, 0, 0);
}

__device__ __forceinline__ unsigned cvtpk(float lo, float hi) {
    unsigned r;
    asm("v_cvt_pk_bf16_f32 %0, %1, %2" : "=v"(r) : "v"(lo), "v"(hi));
    return r;
}
__device__ __forceinline__ void pswap(unsigned &a, unsigned &b) {
    asm("v_permlane32_swap_b32 %0, %1" : "+v"(a), "+v"(b));
}
__device__ __forceinline__ bf16x8 mkpa(unsigned w0, unsigned w1, unsigned w2, unsigned w3) {
    union { unsigned u[4]; bf16x8 h; } cv;
    cv.u[0] = w0; cv.u[1] = w1; cv.u[2] = w2; cv.u[3] = w3;
    return cv.h;
}

// ---------------- conversion: f32 -> bf16 (vectorized) ----------------
__global__ __launch_bounds__(256) void convert_bf16_kernel(
    const float* __restrict__ in, unsigned short* __restrict__ out, int n4) {
    int i = blockIdx.x * 256 + threadIdx.x;
    if (i < n4) {
        float4 v = reinterpret_cast<const float4*>(in)[i];
        ushort4 o;
        o.x = f2b(v.x); o.y = f2b(v.y); o.z = f2b(v.z); o.w = f2b(v.w);
        reinterpret_cast<ushort4*>(out)[i] = o;
    }
}

// ---------------- transpose + convert: W[R][C] f32 -> Wt[C][R] bf16 ----------------
__global__ __launch_bounds__(256) void transpose_bf16_kernel(
    const float* __restrict__ in, unsigned short* __restrict__ out, int R, int C) {
    __shared__ float tile[32][33];
    int c0 = blockIdx.x * 32, r0 = blockIdx.y * 32;
    int tx = threadIdx.x & 31, ty = threadIdx.x >> 5;  // 32 x 8
    #pragma unroll
    for (int i = ty; i < 32; i += 8)
        tile[i][tx] = in[(size_t)(r0 + i) * C + c0 + tx];
    __syncthreads();
    #pragma unroll
    for (int i = ty; i < 32; i += 8)
        out[(size_t)(c0 + i) * R + r0 + tx] = f2b(tile[tx][i]);
}

// ============ 256x256-tile GEMM, 8 waves, BK=64, double-buffered LDS + counted vmcnt ============
// EPI 0: bf16 out + bias + relu. EPI 1: QKV head-split (section uniform per block since
// 768 = 3*256). EPI 2: f32 partial (split-K), no bias.
#define STG256(buf, kt)                                                                  \
    {                                                                                    \
        const char* ga = (const char*)(A + (size_t)bm * lda + koff + ((kt) << 6));       \
        const char* gb = (const char*)(Bt + (size_t)bn * ldb + koff + ((kt) << 6));      \
        char* la = (char*)Sh + (buf) * 65536 + t * 16;                                   \
        char* lb = la + 32768;                                                           \
        _Pragma("unroll")                                                                \
        for (int p = 0; p < 4; ++p)                                                      \
            gload16(ga + (size_t)(sr + p * 64) * la2 + scb, la + p * 8192);              \
        _Pragma("unroll")                                                                \
        for (int p = 0; p < 4; ++p)                                                      \
            gload16(gb + (size_t)(sr + p * 64) * lb2 + scb, lb + p * 8192);              \
    }

template <int EPI>
__global__ __launch_bounds__(512, 2) void gemm256(
    const unsigned short* __restrict__ A, int lda,
    const unsigned short* __restrict__ Bt, int ldb,
    const float* __restrict__ bias0, const float* __restrict__ bias1,
    const float* __restrict__ bias2,
    unsigned short* __restrict__ ob0, unsigned short* __restrict__ ob1,
    unsigned short* __restrict__ ob2, float* __restrict__ of,
    int M, int N, int Ksub, float qscale) {
    __shared__ __align__(16) unsigned short Sh[2 * 32768];  // 128 KB: 2 bufs x (A 16K + B 16K els)
    const int t = threadIdx.x;
    const int wave = t >> 6, lane = t & 63;
    const int wr = wave >> 2, wc = wave & 3;
    const int bn = blockIdx.x * 256, bm = blockIdx.y * 256;
    const int koff = (EPI == 2) ? blockIdx.z * Ksub : 0;
    const int lr = lane & 15;
    const int lk8 = (lane >> 4) << 3;
    const int sr = t >> 3;
    const int scb = (t & 7) * 16;
    const size_t la2 = (size_t)lda * 2, lb2 = (size_t)ldb * 2;

    f32x4 acc[8][4];
    #pragma unroll
    for (int i = 0; i < 8; ++i)
        #pragma unroll
        for (int j = 0; j < 4; ++j) { f32x4 z = {0.f, 0.f, 0.f, 0.f}; acc[i][j] = z; }

    const int nkt = Ksub >> 6;
    STG256(0, 0)
    for (int kt = 0; kt < nkt; ++kt) {
        const int cur = kt & 1;
        if (kt + 1 < nkt) {
            STG256(cur ^ 1, kt + 1)
            asm volatile("s_waitcnt vmcnt(8)" ::: "memory");
        } else {
            asm volatile("s_waitcnt vmcnt(0)" ::: "memory");
        }
        __builtin_amdgcn_s_barrier();
        __builtin_amdgcn_sched_barrier(0);
        const unsigned short* Ab = Sh + cur * 32768;
        const unsigned short* Bb = Ab + 16384;
        #pragma unroll
        for (int ks = 0; ks < 64; ks += 32) {
            bf16x8 af[8], bfv[4];
            #pragma unroll
            for (int i = 0; i < 8; ++i)
                af[i] = *reinterpret_cast<const bf16x8*>(&Ab[(wr * 128 + i * 16 + lr) * 64 + ks + lk8]);
            #pragma unroll
            for (int j = 0; j < 4; ++j)
                bfv[j] = *reinterpret_cast<const bf16x8*>(&Bb[(wc * 64 + j * 16 + lr) * 64 + ks + lk8]);
            __builtin_amdgcn_s_setprio(1);
            #pragma unroll
            for (int i = 0; i < 8; ++i)
                #pragma unroll
                for (int j = 0; j < 4; ++j)
                    acc[i][j] = __builtin_amdgcn_mfma_f32_16x16x32_bf16(af[i], bfv[j], acc[i][j], 0, 0, 0);
            __builtin_amdgcn_s_setprio(0);
        }
        __builtin_amdgcn_s_barrier();
    }

    const int r0 = (lane >> 4) << 2;
    if (EPI == 0) {  // bf16 + bias + relu
        #pragma unroll
        for (int i = 0; i < 8; ++i) {
            const int row_b = bm + wr * 128 + i * 16 + r0;
            #pragma unroll
            for (int j = 0; j < 4; ++j) {
                const int col = bn + wc * 64 + j * 16 + lr;
                const float bvv = bias0[col];
                #pragma unroll
                for (int r = 0; r < 4; ++r) {
                    float vv = acc[i][j][r] + bvv;
                    vv = vv > 0.f ? vv : 0.f;
                    ob0[(size_t)(row_b + r) * N + col] = f2b(vv);
                }
            }
        }
    } else if (EPI == 1) {  // QKV head-split
        const int sec = (bn >= 2 * DM) ? 2 : (bn >= DM ? 1 : 0);
        const int nb = bn - sec * DM;
        const float* bias = (sec == 0) ? bias0 : (sec == 1 ? bias1 : bias2);
        #pragma unroll
        for (int i = 0; i < 8; ++i) {
            const int row_b = bm + wr * 128 + i * 16 + r0;
            const int b = row_b >> 11, s = row_b & 2047;
            #pragma unroll
            for (int j = 0; j < 4; ++j) {
                const int c768 = nb + wc * 64 + j * 16 + lr;
                const int h = c768 >> 6, d = c768 & 63;
                const float bvv = bias[c768];
                if (sec == 2) {
                    ushort4 w;
                    w.x = f2b(acc[i][j][0] + bvv);
                    w.y = f2b(acc[i][j][1] + bvv);
                    w.z = f2b(acc[i][j][2] + bvv);
                    w.w = f2b(acc[i][j][3] + bvv);
                    *reinterpret_cast<ushort4*>(
                        ob2 + (((size_t)(b * NH + h) * DKH) + d) * S_LEN + s) = w;
                } else {
                    const float sc = (sec == 0) ? qscale : 1.f;
                    unsigned short* dst = (sec == 0) ? ob0 : ob1;
                    #pragma unroll
                    for (int r = 0; r < 4; ++r)
                        dst[(((size_t)(b * NH + h) * S_LEN) + s + r) * DKH + d] =
                            f2b((acc[i][j][r] + bvv) * sc);
                }
            }
        }
    } else {  // f32 partial
        float* op = of + (size_t)blockIdx.z * M * N;
        #pragma unroll
        for (int i = 0; i < 8; ++i) {
            const int row_b = bm + wr * 128 + i * 16 + r0;
            #pragma unroll
            for (int j = 0; j < 4; ++j) {
                const int col = bn + wc * 64 + j * 16 + lr;
                #pragma unroll
                for (int r = 0; r < 4; ++r)
                    op[(size_t)(row_b + r) * N + col] = acc[i][j][r];
            }
        }
    }
}

// ============ BM=128 x BN=64 (N=768 GEMMs: WO) ============
template <int RELU, int RES, int EF32, int EB16>
__global__ __launch_bounds__(256) void gemm_bt64(
    const unsigned short* __restrict__ A, const unsigned short* __restrict__ Bt,
    const float* __restrict__ bias, const float* __restrict__ res,
    float* __restrict__ outf, unsigned short* __restrict__ outb,
    int M, int N, int K) {
    __shared__ __align__(16) unsigned short As[128 * 64];
    __shared__ __align__(16) unsigned short Bs[64 * 64];
    const int t = threadIdx.x;
    const int wave = t >> 6, lane = t & 63;
    const int bn = blockIdx.x * 64, bm = blockIdx.y * 128;
    const int lr = lane & 15;
    const int lk8 = (lane >> 4) << 3;
    const int srow = t >> 3;
    const int scol = (t & 7) * 16;
    f32x4 acc[2][4];
    #pragma unroll
    for (int i = 0; i < 2; ++i)
        #pragma unroll
        for (int j = 0; j < 4; ++j) { f32x4 z = {0.f, 0.f, 0.f, 0.f}; acc[i][j] = z; }
    const int nkt = K >> 6;
    for (int kt = 0; kt < nkt; ++kt) {
        const char* ga = (const char*)(A + (size_t)bm * K + (kt << 6));
        const char* gb = (const char*)(Bt + (size_t)bn * K + (kt << 6));
        const size_t K2 = (size_t)K * 2;
        #pragma unroll
        for (int p = 0; p < 4; ++p)
            gload16(ga + (size_t)(srow + p * 32) * K2 + scol, (char*)As + p * 4096 + t * 16);
        #pragma unroll
        for (int p = 0; p < 2; ++p)
            gload16(gb + (size_t)(srow + p * 32) * K2 + scol, (char*)Bs + p * 4096 + t * 16);
        __syncthreads();
        #pragma unroll
        for (int ks = 0; ks < 64; ks += 32) {
            bf16x8 af[2], bfv[4];
            #pragma unroll
            for (int i = 0; i < 2; ++i)
                af[i] = *reinterpret_cast<const bf16x8*>(&As[(wave * 32 + i * 16 + lr) * 64 + ks + lk8]);
            #pragma unroll
            for (int j = 0; j < 4; ++j)
                bfv[j] = *reinterpret_cast<const bf16x8*>(&Bs[(j * 16 + lr) * 64 + ks + lk8]);
            #pragma unroll
            for (int i = 0; i < 2; ++i)
                #pragma unroll
                for (int j = 0; j < 4; ++j)
                    acc[i][j] = __builtin_amdgcn_mfma_f32_16x16x32_bf16(af[i], bfv[j], acc[i][j], 0, 0, 0);
        }
        __syncthreads();
    }
    const int r0 = (lane >> 4) << 2;
    #pragma unroll
    for (int i = 0; i < 2; ++i) {
        const int row_b = bm + wave * 32 + i * 16 + r0;
        #pragma unroll
        for (int j = 0; j < 4; ++j) {
            const int col = bn + j * 16 + lr;
            const float bvv = bias[col];
            #pragma unroll
            for (int r = 0; r < 4; ++r) {
                float vv = acc[i][j][r] + bvv;
                if (RES) vv += res[(size_t)(row_b + r) * N + col];
                if (RELU) vv = vv > 0.f ? vv : 0.f;
                if (EF32) outf[(size_t)(row_b + r) * N + col] = vv;
                if (EB16) outb[(size_t)(row_b + r) * N + col] = f2b(vv);
            }
        }
    }
}

// ---------------- MFMA causal flash attention: 32x32 in-register, K reg-dbuf ----------------
#define ALOADK(dst, k0v)                                                     \
    _Pragma("unroll") for (int kh = 0; kh < 2; ++kh)                         \
        _Pragma("unroll") for (int c = 0; c < 4; ++c)                        \
            dst[kh][c] = *reinterpret_cast<const bf16x8*>(                   \
                kb + (size_t)((k0v) + kh * 32 + x) * DKH + c * 16 + k8);
#define ALOADV(dst, k0v)                                                     \
    _Pragma("unroll") for (int dt = 0; dt < 2; ++dt)                         \
        _Pragma("unroll") for (int s = 0; s < 4; ++s)                        \
            dst[dt][s] = *reinterpret_cast<const bf16x8*>(                   \
                vbg + (size_t)(dt * 32 + x) * S_LEN + (k0v) + s * 16 + k8);

__global__ __launch_bounds__(64) void attn_mfma_kernel(
    const unsigned short* __restrict__ q16,   // [B,H,S,64]
    const unsigned short* __restrict__ k16,   // [B,H,S,64]
    const unsigned short* __restrict__ vt16,  // [B,H,64,S]
    unsigned short* __restrict__ ctx16) {     // [B,S,DM]
    const int lane = threadIdx.x & 63;
    const int bh = blockIdx.x;
    const int qb = (gridDim.y - 1) - blockIdx.y;
    const int b = bh / NH, h = bh % NH;
    const size_t hbase = (size_t)bh * S_LEN * DKH;
    const int x = lane & 31;
    const int hi = lane >> 5;
    const int k8 = hi << 3;
    const int sW = qb << 5;
    const int qg = sW + x;

    bf16x8 qa[4];
    #pragma unroll
    for (int c = 0; c < 4; ++c)
        qa[c] = *reinterpret_cast<const bf16x8*>(
            q16 + hbase + (size_t)(sW + x) * DKH + c * 16 + k8);

    float mst = -3e38f, lst = 0.f;
    f32x16 acc0, acc1;
    #pragma unroll
    for (int r = 0; r < 16; ++r) { acc0[r] = 0.f; acc1[r] = 0.f; }

    const unsigned short* kb = k16 + hbase;
    const unsigned short* vbg = vt16 + hbase;
    const int nt = (sW >> 6) + 1;

    bf16x8 kac[2][4];   // current K (loaded one tile ahead)
    ALOADK(kac, 0)
    for (int kt = 0; kt < nt; ++kt) {
        const int k0 = kt << 6;
        // current V issued at top: latency hides under QK + softmax
        bf16x8 vac[2][4];
        ALOADV(vac, k0)
        // next K issued before softmax: latency hides under softmax + PV
        bf16x8 kan[2][4];
        if (kt + 1 < nt) { ALOADK(kan, k0 + 64) }

        f32x16 sc0, sc1;
        #pragma unroll
        for (int r = 0; r < 16; ++r) { sc0[r] = 0.f; sc1[r] = 0.f; }
        __builtin_amdgcn_s_setprio(1);
        #pragma unroll
        for (int c = 0; c < 4; ++c) {
            sc0 = __builtin_amdgcn_mfma_f32_32x32x16_bf16(kac[0][c], qa[c], sc0, 0, 0, 0);
            sc1 = __builtin_amdgcn_mfma_f32_32x32x16_bf16(kac[1][c], qa[c], sc1, 0, 0, 0);
        }
        __builtin_amdgcn_s_setprio(0);

        if (kt == nt - 1) {
            #pragma unroll
            for (int r = 0; r < 16; ++r) {
                const int cr = (r & 3) + (hi << 2) + ((r >> 2) << 3);
                if (k0 + cr > qg) sc0[r] = -3e38f;
                if (k0 + 32 + cr > qg) sc1[r] = -3e38f;
            }
        }

        float tm = fmaxf(sc0[0], sc0[1]);
        #pragma unroll
        for (int r = 2; r < 16; ++r) tm = fmaxf(tm, sc0[r]);
        #pragma unroll
        for (int r = 0; r < 16; ++r) tm = fmaxf(tm, sc1[r]);
        tm = fmaxf(tm, __shfl_xor(tm, 32));

        if (!__all(tm <= mst + 8.f)) {
            const float mn = fmaxf(mst, tm);
            const float corr = exp2f(mst - mn);
            mst = mn;
            lst *= corr;
            float cw[16];
            #pragma unroll
            for (int r = 0; r < 16; ++r)
                cw[r] = __shfl(corr, (r & 3) + (hi << 2) + ((r >> 2) << 3));
            #pragma unroll
            for (int r = 0; r < 16; ++r) { acc0[r] *= cw[r]; acc1[r] *= cw[r]; }
        }

        float ts = 0.f;
        #pragma unroll
        for (int r = 0; r < 16; ++r) {
            sc0[r] = exp2f(sc0[r] - mst); ts += sc0[r];
            sc1[r] = exp2f(sc1[r] - mst); ts += sc1[r];
        }
        ts += __shfl_xor(ts, 32);
        lst += ts;

        unsigned a0 = cvtpk(sc0[0], sc0[1]),   b0 = cvtpk(sc0[4], sc0[5]);   pswap(a0, b0);
        unsigned a1 = cvtpk(sc0[2], sc0[3]),   b1 = cvtpk(sc0[6], sc0[7]);   pswap(a1, b1);
        unsigned a2 = cvtpk(sc0[8], sc0[9]),   b2 = cvtpk(sc0[12], sc0[13]); pswap(a2, b2);
        unsigned a3 = cvtpk(sc0[10], sc0[11]), b3 = cvtpk(sc0[14], sc0[15]); pswap(a3, b3);
        bf16x8 pa00 = mkpa(a0, a1, b0, b1);
        bf16x8 pa01 = mkpa(a2, a3, b2, b3);
        unsigned c0 = cvtpk(sc1[0], sc1[1]),   d0 = cvtpk(sc1[4], sc1[5]);   pswap(c0, d0);
        unsigned c1 = cvtpk(sc1[2], sc1[3]),   d1 = cvtpk(sc1[6], sc1[7]);   pswap(c1, d1);
        unsigned c2 = cvtpk(sc1[8], sc1[9]),   d2 = cvtpk(sc1[12], sc1[13]); pswap(c2, d2);
        unsigned c3 = cvtpk(sc1[10], sc1[11]), d3 = cvtpk(sc1[14], sc1[15]); pswap(c3, d3);
        bf16x8 pa10 = mkpa(c0, c1, d0, d1);
        bf16x8 pa11 = mkpa(c2, c3, d2, d3);

        __builtin_amdgcn_s_setprio(1);
        acc0 = __builtin_amdgcn_mfma_f32_32x32x16_bf16(pa00, vac[0][0], acc0, 0, 0, 0);
        acc1 = __builtin_amdgcn_mfma_f32_32x32x16_bf16(pa00, vac[1][0], acc1, 0, 0, 0);
        acc0 = __builtin_amdgcn_mfma_f32_32x32x16_bf16(pa01, vac[0][1], acc0, 0, 0, 0);
        acc1 = __builtin_amdgcn_mfma_f32_32x32x16_bf16(pa01, vac[1][1], acc1, 0, 0, 0);
        acc0 = __builtin_amdgcn_mfma_f32_32x32x16_bf16(pa10, vac[0][2], acc0, 0, 0, 0);
        acc1 = __builtin_amdgcn_mfma_f32_32x32x16_bf16(pa10, vac[1][2], acc1, 0, 0, 0);
        acc0 = __builtin_amdgcn_mfma_f32_32x32x16_bf16(pa11, vac[0][3], acc0, 0, 0, 0);
        acc1 = __builtin_amdgcn_mfma_f32_32x32x16_bf16(pa11, vac[1][3], acc1, 0, 0, 0);
        __builtin_amdgcn_s_setprio(0);

        if (kt + 1 < nt) {
            #pragma unroll
            for (int kh = 0; kh < 2; ++kh)
                #pragma unroll
                for (int c = 0; c < 4; ++c) kac[kh][c] = kan[kh][c];
        }
    }

    const float li = 1.f / lst;
    float lw[16];
    #pragma unroll
    for (int r = 0; r < 16; ++r)
        lw[r] = __shfl(li, (r & 3) + (hi << 2) + ((r >> 2) << 3));
    #pragma unroll
    for (int r = 0; r < 16; ++r) {
        const int q = sW + (r & 3) + (hi << 2) + ((r >> 2) << 3);
        const size_t rowb = ((size_t)b * S_LEN + q) * DM + h * DKH;
        ctx16[rowb + x] = f2b(acc0[r] * lw[r]);
        ctx16[rowb + 32 + x] = f2b(acc1[r] * lw[r]);
    }
}

// ---------------- row LayerNorm (LN1), optional bf16 copy ----------------
template <int EB16>
__global__ __launch_bounds__(256) void layernorm_kernel(
    const float* __restrict__ in, const float* __restrict__ gam, const float* __restrict__ bet,
    float* __restrict__ outf, unsigned short* __restrict__ outb) {
    __shared__ float red[8];
    const int row = blockIdx.x, t = threadIdx.x;
    const int wave = t >> 6, lane = t & 63;
    const float* p = in + (size_t)row * DM;
    const float v0 = p[t], v1 = p[t + 256], v2 = p[t + 512];
    float s = v0 + v1 + v2;
    float sq = v0 * v0 + v1 * v1 + v2 * v2;
    #pragma unroll
    for (int off = 32; off > 0; off >>= 1) { s += __shfl_xor(s, off); sq += __shfl_xor(sq, off); }
    if (lane == 0) { red[wave] = s; red[wave + 4] = sq; }
    __syncthreads();
    s = red[0] + red[1] + red[2] + red[3];
    sq = red[4] + red[5] + red[6] + red[7];
    const float mu = s * (1.f / DM);
    const float var = sq * (1.f / DM) - mu * mu;
    const float rs = rsqrtf(var + 1e-5f);
    #pragma unroll
    for (int i = 0; i < 3; ++i) {
        const int c = t + i * 256;
        const float vv = (i == 0 ? v0 : (i == 1 ? v1 : v2));
        const float y = (vv - mu) * rs * gam[c] + bet[c];
        outf[(size_t)row * DM + c] = y;
        if (EB16) outb[(size_t)row * DM + c] = f2b(y);
    }
}

// ---------------- LN2 fused with split-K merge: out = LN(sum(parts) + bias + res) ----------------
__global__ __launch_bounds__(256) void ln2_merge_kernel(
    const float* __restrict__ part, size_t pstride, int ns,
    const float* __restrict__ res, const float* __restrict__ bias,
    const float* __restrict__ gam, const float* __restrict__ bet,
    float* __restrict__ outf) {
    __shared__ float red[8];
    const int row = blockIdx.x, t = threadIdx.x;
    const int wave = t >> 6, lane = t & 63;
    float v[3];
    #pragma unroll
    for (int i = 0; i < 3; ++i) {
        const int c = t + i * 256;
        float sv = res[(size_t)row * DM + c] + bias[c];
        for (int z = 0; z < ns; ++z)
            sv += part[(size_t)z * pstride + (size_t)row * DM + c];
        v[i] = sv;
    }
    float s = v[0] + v[1] + v[2];
    float sq = v[0] * v[0] + v[1] * v[1] + v[2] * v[2];
    #pragma unroll
    for (int off = 32; off > 0; off >>= 1) { s += __shfl_xor(s, off); sq += __shfl_xor(sq, off); }
    if (lane == 0) { red[wave] = s; red[wave + 4] = sq; }
    __syncthreads();
    s = red[0] + red[1] + red[2] + red[3];
    sq = red[4] + red[5] + red[6] + red[7];
    const float mu = s * (1.f / DM);
    const float var = sq * (1.f / DM) - mu * mu;
    const float rs = rsqrtf(var + 1e-5f);
    #pragma unroll
    for (int i = 0; i < 3; ++i) {
        const int c = t + i * 256;
        outf[(size_t)row * DM + c] = (v[i] - mu) * rs * gam[c] + bet[c];
    }
}

extern "C" void kernel_launch(void* const* d_in, const int* in_sizes, int n_in,
                              void* d_out, int out_size, void* d_ws, size_t ws_size,
                              hipStream_t stream) {
    const float* x   = (const float*)d_in[0];
    const float* wq  = (const float*)d_in[1];
    const float* bq  = (const float*)d_in[2];
    const float* wk  = (const float*)d_in[3];
    const float* bk  = (const float*)d_in[4];
    const float* wv  = (const float*)d_in[5];
    const float* bv  = (const float*)d_in[6];
    const float* wo  = (const float*)d_in[7];
    const float* bo  = (const float*)d_in[8];
    const float* w1  = (const float*)d_in[9];
    const float* b1  = (const float*)d_in[10];
    const float* w2  = (const float*)d_in[11];
    const float* b2  = (const float*)d_in[12];
    const float* g1  = (const float*)d_in[13];
    const float* be1 = (const float*)d_in[14];
    const float* g2  = (const float*)d_in[15];
    const float* be2 = (const float*)d_in[16];

    char* wp = (char*)d_ws;
    auto alloc = [&](size_t bytes) -> void* {
        void* r = (void*)wp;
        wp += (bytes + 255) & ~(size_t)255;
        return r;
    };
    const int M = MROWS;
    unsigned short* wqkv16 = (unsigned short*)alloc((size_t)3 * DM * DM * 2);  // [2304][768]
    unsigned short* wo16 = (unsigned short*)alloc((size_t)DM * DM * 2);
    unsigned short* w116 = (unsigned short*)alloc((size_t)DM * DFF * 2);
    unsigned short* w216 = (unsigned short*)alloc((size_t)DM * DFF * 2);
    unsigned short* ctx16 = (unsigned short*)alloc((size_t)M * DM * 2);
    float* y1 = (float*)alloc((size_t)M * DM * 4);
    unsigned short* x16  = (unsigned short*)alloc((size_t)M * DM * 2);
    unsigned short* q16  = (unsigned short*)alloc((size_t)M * DM * 2);
    unsigned short* k16  = (unsigned short*)alloc((size_t)M * DM * 2);
    unsigned short* vt16 = (unsigned short*)alloc((size_t)M * DM * 2);
    unsigned short* ff116 = x16;    // [M,DFF] bf16 over x16..vt16 (contiguous, dead after attn)
    unsigned short* x116  = ctx16;  // LN1 bf16 output

    // split-K partials for FFN2, gated on workspace size
    const size_t per = (size_t)M * DM * 4;
    size_t used = (size_t)(wp - (char*)d_ws);
    int NS = 1;
    if (used + 4 * per + 1024 <= ws_size) NS = 4;
    else if (used + 2 * per + 1024 <= ws_size) NS = 2;
    float* part = (float*)alloc((size_t)NS * per);

    convert_bf16_kernel<<<(M * DM / 4 + 255) / 256, 256, 0, stream>>>(x, x16, M * DM / 4);
    transpose_bf16_kernel<<<dim3(DM / 32, DM / 32), 256, 0, stream>>>(wq, wqkv16, DM, DM);
    transpose_bf16_kernel<<<dim3(DM / 32, DM / 32), 256, 0, stream>>>(wk, wqkv16 + (size_t)DM * DM, DM, DM);
    transpose_bf16_kernel<<<dim3(DM / 32, DM / 32), 256, 0, stream>>>(wv, wqkv16 + (size_t)2 * DM * DM, DM, DM);
    transpose_bf16_kernel<<<dim3(DM / 32, DM / 32), 256, 0, stream>>>(wo, wo16, DM, DM);
    transpose_bf16_kernel<<<dim3(DFF / 32, DM / 32), 256, 0, stream>>>(w1, w116, DM, DFF);
    transpose_bf16_kernel<<<dim3(DM / 32, DFF / 32), 256, 0, stream>>>(w2, w216, DFF, DM);

    const float QSCALE = 0.125f * 1.44269504088896f;
    // QKV: 256^2 tile, N=2304 -> 9x16 = 144 blocks (one round)
    gemm256<1><<<dim3(3 * DM / 256, M / 256), 512, 0, stream>>>(
        x16, DM, wqkv16, DM, bq, bk, bv, q16, k16, vt16, nullptr, M, 3 * DM, DM, QSCALE);

    attn_mfma_kernel<<<dim3(BATCH * NH, S_LEN / 32), 64, 0, stream>>>(q16, k16, vt16, ctx16);

    gemm_bt64<0, 1, 1, 0><<<dim3(DM / 64, M / 128), 256, 0, stream>>>(
        ctx16, wo16, bo, x, y1, nullptr, M, DM, DM);
    layernorm_kernel<1><<<M, 256, 0, stream>>>(y1, g1, be1, y1, x116);

    // FFN1: 256^2, N=3072 -> 12x16 = 192 blocks
    gemm256<0><<<dim3(DFF / 256, M / 256), 512, 0, stream>>>(
        x116, DM, w116, DM, b1, nullptr, nullptr, ff116, nullptr, nullptr, nullptr, M, DFF, DM, 1.f);

    // FFN2: 256^2 split-K=NS -> 3x16xNS blocks, f32 partials
    gemm256<2><<<dim3(DM / 256, M / 256, NS), 512, 0, stream>>>(
        ff116, DFF, w216, DFF, nullptr, nullptr, nullptr, nullptr, nullptr, nullptr, part,
        M, DM, DFF / NS, 1.f);
    // LN2 fused merge: LN(sum parts + b2 + y1) -> d_out
    ln2_merge_kernel<<<M, 256, 0, stream>>>(part, per / 4, NS, y1, b2, g2, be2, (float*)d_out);
}

// Round 9
// 219.301 us; speedup vs baseline: 1.4466x; 1.0734x over previous
//
#include <hip/hip_runtime.h>
#include <stdint.h>

#define S_LEN 2048
#define BATCH 2
#define DM 768
#define NH 12
#define DKH 64
#define DFF 3072
#define MROWS (BATCH * S_LEN)  // 4096

typedef short bf16x8 __attribute__((ext_vector_type(8)));
typedef float f32x4 __attribute__((ext_vector_type(4)));
typedef float f32x16 __attribute__((ext_vector_type(16)));

__device__ __forceinline__ unsigned short f2b(float f) {
    union { float f; unsigned u; } cv; cv.f = f;
    unsigned u = cv.u;
    unsigned r = (u + 0x7FFFu + ((u >> 16) & 1u)) >> 16;  // RNE
    return (unsigned short)r;
}

__device__ __forceinline__ void gload16(const void* g, void* l) {
    __builtin_amdgcn_global_load_lds(
        (const __attribute__((address_space(1))) unsigned int*)g,
        (__attribute__((address_space(3))) unsigned int*)l, 16, 0, 0);
}

__device__ __forceinline__ unsigned cvtpk(float lo, float hi) {
    unsigned r;
    asm("v_cvt_pk_bf16_f32 %0, %1, %2" : "=v"(r) : "v"(lo), "v"(hi));
    return r;
}
__device__ __forceinline__ void pswap(unsigned &a, unsigned &b) {
    asm("v_permlane32_swap_b32 %0, %1" : "+v"(a), "+v"(b));
}
__device__ __forceinline__ bf16x8 mkpa(unsigned w0, unsigned w1, unsigned w2, unsigned w3) {
    union { unsigned u[4]; bf16x8 h; } cv;
    cv.u[0] = w0; cv.u[1] = w1; cv.u[2] = w2; cv.u[3] = w3;
    return cv.h;
}

// ---------------- fused prep: x f32->bf16 convert + 6 weight transposes ----------------
// blocks [0,3072): convert; [3072,3072+2304): wq/wk/wv/wo 32x32 tiles;
// then w1 (2304), then w2 (2304). Total 9984 blocks.
__global__ __launch_bounds__(256) void prep_kernel(
    const float* __restrict__ x,
    const float* __restrict__ wq, const float* __restrict__ wk,
    const float* __restrict__ wv, const float* __restrict__ wo,
    const float* __restrict__ w1, const float* __restrict__ w2,
    unsigned short* __restrict__ x16, unsigned short* __restrict__ wqkv16,
    unsigned short* __restrict__ wo16, unsigned short* __restrict__ w116,
    unsigned short* __restrict__ w216) {
    const int t = threadIdx.x;
    int bid = blockIdx.x;
    if (bid < 3072) {
        const int i = bid * 256 + t;  // n4 = 786432
        float4 v = reinterpret_cast<const float4*>(x)[i];
        ushort4 o;
        o.x = f2b(v.x); o.y = f2b(v.y); o.z = f2b(v.z); o.w = f2b(v.w);
        reinterpret_cast<ushort4*>(x16)[i] = o;
        return;
    }
    bid -= 3072;
    const float* in; unsigned short* out; int R, C, bx, by;
    if (bid < 2304) {  // 4 square weights, 576 tiles each
        const int wsel = bid / 576, r = bid % 576;
        in = (wsel == 0) ? wq : (wsel == 1) ? wk : (wsel == 2) ? wv : wo;
        out = (wsel == 3) ? wo16 : wqkv16 + (size_t)wsel * DM * DM;
        R = DM; C = DM; bx = r % 24; by = r / 24;
    } else if (bid < 4608) {
        const int r = bid - 2304;
        in = w1; out = w116; R = DM; C = DFF; bx = r % 96; by = r / 96;
    } else {
        const int r = bid - 4608;
        in = w2; out = w216; R = DFF; C = DM; bx = r % 24; by = r / 24;
    }
    __shared__ float tile[32][33];
    const int c0 = bx * 32, r0 = by * 32;
    const int tx = t & 31, ty = t >> 5;
    #pragma unroll
    for (int i = ty; i < 32; i += 8)
        tile[i][tx] = in[(size_t)(r0 + i) * C + c0 + tx];
    __syncthreads();
    #pragma unroll
    for (int i = ty; i < 32; i += 8)
        out[(size_t)(c0 + i) * R + r0 + tx] = f2b(tile[tx][i]);
}

// ============ 256x192-tile GEMM, 8 waves (2Mx4N, per-wave 128x48), BK=64 ============
// Double-buffered LDS (112 KB) + counted vmcnt(7). EPI 0: bf16+bias+relu.
// EPI 1: QKV head-split (section uniform per block: 768 = 4*192). EPI 2: f32 partial.
#define STG192(buf, kt)                                                                  \
    {                                                                                    \
        const char* ga = (const char*)(A + (size_t)bm * lda + koff + ((kt) << 6));       \
        const char* gb = (const char*)(Bt + (size_t)bn * ldb + koff + ((kt) << 6));      \
        char* la = (char*)Sh + (buf) * 57344 + t * 16;                                   \
        char* lb = (char*)Sh + (buf) * 57344 + 32768 + t * 16;                           \
        _Pragma("unroll")                                                                \
        for (int p = 0; p < 4; ++p)                                                      \
            gload16(ga + (size_t)(sr + p * 64) * la2 + scb, la + p * 8192);              \
        _Pragma("unroll")                                                                \
        for (int p = 0; p < 3; ++p)                                                      \
            gload16(gb + (size_t)(sr + p * 64) * lb2 + scb, lb + p * 8192);              \
    }

template <int EPI>
__global__ __launch_bounds__(512, 2) void gemm192(
    const unsigned short* __restrict__ A, int lda,
    const unsigned short* __restrict__ Bt, int ldb,
    const float* __restrict__ bias0, const float* __restrict__ bias1,
    const float* __restrict__ bias2,
    unsigned short* __restrict__ ob0, unsigned short* __restrict__ ob1,
    unsigned short* __restrict__ ob2, float* __restrict__ of,
    int M, int N, int Ksub, float qscale) {
    __shared__ __align__(16) unsigned short Sh[2 * 28672];  // 112 KB
    const int t = threadIdx.x;
    const int wave = t >> 6, lane = t & 63;
    const int wr = wave >> 2, wc = wave & 3;
    const int bn = blockIdx.x * 192, bm = blockIdx.y * 256;
    const int koff = (EPI == 2) ? blockIdx.z * Ksub : 0;
    const int lr = lane & 15;
    const int lk8 = (lane >> 4) << 3;
    const int sr = t >> 3;
    const int scb = (t & 7) * 16;
    const size_t la2 = (size_t)lda * 2, lb2 = (size_t)ldb * 2;

    f32x4 acc[8][3];
    #pragma unroll
    for (int i = 0; i < 8; ++i)
        #pragma unroll
        for (int j = 0; j < 3; ++j) { f32x4 z = {0.f, 0.f, 0.f, 0.f}; acc[i][j] = z; }

    const int nkt = Ksub >> 6;
    STG192(0, 0)
    for (int kt = 0; kt < nkt; ++kt) {
        const int cur = kt & 1;
        if (kt + 1 < nkt) {
            STG192(cur ^ 1, kt + 1)
            asm volatile("s_waitcnt vmcnt(7)" ::: "memory");
        } else {
            asm volatile("s_waitcnt vmcnt(0)" ::: "memory");
        }
        __builtin_amdgcn_s_barrier();
        __builtin_amdgcn_sched_barrier(0);
        const unsigned short* Ab = Sh + cur * 28672;
        const unsigned short* Bb = Ab + 16384;
        #pragma unroll
        for (int ks = 0; ks < 64; ks += 32) {
            bf16x8 af[8], bfv[3];
            #pragma unroll
            for (int i = 0; i < 8; ++i)
                af[i] = *reinterpret_cast<const bf16x8*>(&Ab[(wr * 128 + i * 16 + lr) * 64 + ks + lk8]);
            #pragma unroll
            for (int j = 0; j < 3; ++j)
                bfv[j] = *reinterpret_cast<const bf16x8*>(&Bb[(wc * 48 + j * 16 + lr) * 64 + ks + lk8]);
            __builtin_amdgcn_s_setprio(1);
            #pragma unroll
            for (int i = 0; i < 8; ++i)
                #pragma unroll
                for (int j = 0; j < 3; ++j)
                    acc[i][j] = __builtin_amdgcn_mfma_f32_16x16x32_bf16(af[i], bfv[j], acc[i][j], 0, 0, 0);
            __builtin_amdgcn_s_setprio(0);
        }
        __builtin_amdgcn_s_barrier();
    }

    const int r0 = (lane >> 4) << 2;
    if (EPI == 0) {
        #pragma unroll
        for (int i = 0; i < 8; ++i) {
            const int row_b = bm + wr * 128 + i * 16 + r0;
            #pragma unroll
            for (int j = 0; j < 3; ++j) {
                const int col = bn + wc * 48 + j * 16 + lr;
                const float bvv = bias0[col];
                #pragma unroll
                for (int r = 0; r < 4; ++r) {
                    float vv = acc[i][j][r] + bvv;
                    vv = vv > 0.f ? vv : 0.f;
                    ob0[(size_t)(row_b + r) * N + col] = f2b(vv);
                }
            }
        }
    } else if (EPI == 1) {
        const int sec = (bn >= 2 * DM) ? 2 : (bn >= DM ? 1 : 0);
        const int nb = bn - sec * DM;
        const float* bias = (sec == 0) ? bias0 : (sec == 1 ? bias1 : bias2);
        #pragma unroll
        for (int i = 0; i < 8; ++i) {
            const int row_b = bm + wr * 128 + i * 16 + r0;
            const int b = row_b >> 11, s = row_b & 2047;
            #pragma unroll
            for (int j = 0; j < 3; ++j) {
                const int c768 = nb + wc * 48 + j * 16 + lr;
                const int h = c768 >> 6, d = c768 & 63;
                const float bvv = bias[c768];
                if (sec == 2) {
                    ushort4 w;
                    w.x = f2b(acc[i][j][0] + bvv);
                    w.y = f2b(acc[i][j][1] + bvv);
                    w.z = f2b(acc[i][j][2] + bvv);
                    w.w = f2b(acc[i][j][3] + bvv);
                    *reinterpret_cast<ushort4*>(
                        ob2 + (((size_t)(b * NH + h) * DKH) + d) * S_LEN + s) = w;
                } else {
                    const float sc = (sec == 0) ? qscale : 1.f;
                    unsigned short* dst = (sec == 0) ? ob0 : ob1;
                    #pragma unroll
                    for (int r = 0; r < 4; ++r)
                        dst[(((size_t)(b * NH + h) * S_LEN) + s + r) * DKH + d] =
                            f2b((acc[i][j][r] + bvv) * sc);
                }
            }
        }
    } else {
        float* op = of + (size_t)blockIdx.z * M * N;
        #pragma unroll
        for (int i = 0; i < 8; ++i) {
            const int row_b = bm + wr * 128 + i * 16 + r0;
            #pragma unroll
            for (int j = 0; j < 3; ++j) {
                const int col = bn + wc * 48 + j * 16 + lr;
                #pragma unroll
                for (int r = 0; r < 4; ++r)
                    op[(size_t)(row_b + r) * N + col] = acc[i][j][r];
            }
        }
    }
}

// ============ BM=128 x BN=64 (WO proj) ============
template <int RELU, int RES, int EF32, int EB16>
__global__ __launch_bounds__(256) void gemm_bt64(
    const unsigned short* __restrict__ A, const unsigned short* __restrict__ Bt,
    const float* __restrict__ bias, const float* __restrict__ res,
    float* __restrict__ outf, unsigned short* __restrict__ outb,
    int M, int N, int K) {
    __shared__ __align__(16) unsigned short As[128 * 64];
    __shared__ __align__(16) unsigned short Bs[64 * 64];
    const int t = threadIdx.x;
    const int wave = t >> 6, lane = t & 63;
    const int bn = blockIdx.x * 64, bm = blockIdx.y * 128;
    const int lr = lane & 15;
    const int lk8 = (lane >> 4) << 3;
    const int srow = t >> 3;
    const int scol = (t & 7) * 16;
    f32x4 acc[2][4];
    #pragma unroll
    for (int i = 0; i < 2; ++i)
        #pragma unroll
        for (int j = 0; j < 4; ++j) { f32x4 z = {0.f, 0.f, 0.f, 0.f}; acc[i][j] = z; }
    const int nkt = K >> 6;
    for (int kt = 0; kt < nkt; ++kt) {
        const char* ga = (const char*)(A + (size_t)bm * K + (kt << 6));
        const char* gb = (const char*)(Bt + (size_t)bn * K + (kt << 6));
        const size_t K2 = (size_t)K * 2;
        #pragma unroll
        for (int p = 0; p < 4; ++p)
            gload16(ga + (size_t)(srow + p * 32) * K2 + scol, (char*)As + p * 4096 + t * 16);
        #pragma unroll
        for (int p = 0; p < 2; ++p)
            gload16(gb + (size_t)(srow + p * 32) * K2 + scol, (char*)Bs + p * 4096 + t * 16);
        __syncthreads();
        #pragma unroll
        for (int ks = 0; ks < 64; ks += 32) {
            bf16x8 af[2], bfv[4];
            #pragma unroll
            for (int i = 0; i < 2; ++i)
                af[i] = *reinterpret_cast<const bf16x8*>(&As[(wave * 32 + i * 16 + lr) * 64 + ks + lk8]);
            #pragma unroll
            for (int j = 0; j < 4; ++j)
                bfv[j] = *reinterpret_cast<const bf16x8*>(&Bs[(j * 16 + lr) * 64 + ks + lk8]);
            #pragma unroll
            for (int i = 0; i < 2; ++i)
                #pragma unroll
                for (int j = 0; j < 4; ++j)
                    acc[i][j] = __builtin_amdgcn_mfma_f32_16x16x32_bf16(af[i], bfv[j], acc[i][j], 0, 0, 0);
        }
        __syncthreads();
    }
    const int r0 = (lane >> 4) << 2;
    #pragma unroll
    for (int i = 0; i < 2; ++i) {
        const int row_b = bm + wave * 32 + i * 16 + r0;
        #pragma unroll
        for (int j = 0; j < 4; ++j) {
            const int col = bn + j * 16 + lr;
            const float bvv = bias[col];
            #pragma unroll
            for (int r = 0; r < 4; ++r) {
                float vv = acc[i][j][r] + bvv;
                if (RES) vv += res[(size_t)(row_b + r) * N + col];
                if (RELU) vv = vv > 0.f ? vv : 0.f;
                if (EF32) outf[(size_t)(row_b + r) * N + col] = vv;
                if (EB16) outb[(size_t)(row_b + r) * N + col] = f2b(vv);
            }
        }
    }
}

// ---------------- MFMA causal flash attention: 2-wave KV-split, in-register softmax ----------------
// Block = 32 q-rows of one (b,h), 2 waves. Wave0: K-tiles [0,half), wave1: [half,nt).
// Online-softmax merge via LDS at the end. All r7/r8 per-wave optimizations retained.
#define ALOADK(dst, k0v)                                                     \
    _Pragma("unroll") for (int kh = 0; kh < 2; ++kh)                         \
        _Pragma("unroll") for (int c = 0; c < 4; ++c)                        \
            dst[kh][c] = *reinterpret_cast<const bf16x8*>(                   \
                kb + (size_t)((k0v) + kh * 32 + x) * DKH + c * 16 + k8);
#define ALOADV(dst, k0v)                                                     \
    _Pragma("unroll") for (int dt = 0; dt < 2; ++dt)                         \
        _Pragma("unroll") for (int s = 0; s < 4; ++s)                        \
            dst[dt][s] = *reinterpret_cast<const bf16x8*>(                   \
                vbg + (size_t)(dt * 32 + x) * S_LEN + (k0v) + s * 16 + k8);

__global__ __launch_bounds__(128) void attn_mfma_kernel(
    const unsigned short* __restrict__ q16,   // [B,H,S,64]
    const unsigned short* __restrict__ k16,   // [B,H,S,64]
    const unsigned short* __restrict__ vt16,  // [B,H,64,S]
    unsigned short* __restrict__ ctx16) {     // [B,S,DM]
    __shared__ float Om[32][64];
    __shared__ float Ml[2][32];
    const int tid = threadIdx.x;
    const int wv_ = tid >> 6, lane = tid & 63;
    const int bh = blockIdx.x;
    const int qb = (gridDim.y - 1) - blockIdx.y;
    const int b = bh / NH, h = bh % NH;
    const size_t hbase = (size_t)bh * S_LEN * DKH;
    const int x = lane & 31;
    const int hi = lane >> 5;
    const int k8 = hi << 3;
    const int sW = qb << 5;
    const int qg = sW + x;

    bf16x8 qa[4];
    #pragma unroll
    for (int c = 0; c < 4; ++c)
        qa[c] = *reinterpret_cast<const bf16x8*>(
            q16 + hbase + (size_t)(sW + x) * DKH + c * 16 + k8);

    float mst = -3e38f, lst = 0.f;
    f32x16 acc0, acc1;
    #pragma unroll
    for (int r = 0; r < 16; ++r) { acc0[r] = 0.f; acc1[r] = 0.f; }

    const unsigned short* kb = k16 + hbase;
    const unsigned short* vbg = vt16 + hbase;
    const int nt = (sW >> 6) + 1;
    const int half = (nt + 1) >> 1;
    const int kt0 = wv_ ? half : 0;
    const int kt1 = wv_ ? nt : half;

    bf16x8 kac[2][4];
    if (kt0 < kt1) { ALOADK(kac, kt0 << 6) }
    for (int kt = kt0; kt < kt1; ++kt) {
        const int k0 = kt << 6;
        bf16x8 vac[2][4];
        ALOADV(vac, k0)
        bf16x8 kan[2][4];
        if (kt + 1 < kt1) { ALOADK(kan, (kt + 1) << 6) }

        f32x16 sc0, sc1;
        #pragma unroll
        for (int r = 0; r < 16; ++r) { sc0[r] = 0.f; sc1[r] = 0.f; }
        __builtin_amdgcn_s_setprio(1);
        #pragma unroll
        for (int c = 0; c < 4; ++c) {
            sc0 = __builtin_amdgcn_mfma_f32_32x32x16_bf16(kac[0][c], qa[c], sc0, 0, 0, 0);
            sc1 = __builtin_amdgcn_mfma_f32_32x32x16_bf16(kac[1][c], qa[c], sc1, 0, 0, 0);
        }
        __builtin_amdgcn_s_setprio(0);

        if (kt == nt - 1) {
            #pragma unroll
            for (int r = 0; r < 16; ++r) {
                const int cr = (r & 3) + (hi << 2) + ((r >> 2) << 3);
                if (k0 + cr > qg) sc0[r] = -3e38f;
                if (k0 + 32 + cr > qg) sc1[r] = -3e38f;
            }
        }

        float tm = fmaxf(sc0[0], sc0[1]);
        #pragma unroll
        for (int r = 2; r < 16; ++r) tm = fmaxf(tm, sc0[r]);
        #pragma unroll
        for (int r = 0; r < 16; ++r) tm = fmaxf(tm, sc1[r]);
        tm = fmaxf(tm, __shfl_xor(tm, 32));

        if (!__all(tm <= mst + 8.f)) {
            const float mn = fmaxf(mst, tm);
            const float corr = exp2f(mst - mn);
            mst = mn;
            lst *= corr;
            float cw[16];
            #pragma unroll
            for (int r = 0; r < 16; ++r)
                cw[r] = __shfl(corr, (r & 3) + (hi << 2) + ((r >> 2) << 3));
            #pragma unroll
            for (int r = 0; r < 16; ++r) { acc0[r] *= cw[r]; acc1[r] *= cw[r]; }
        }

        float ts = 0.f;
        #pragma unroll
        for (int r = 0; r < 16; ++r) {
            sc0[r] = exp2f(sc0[r] - mst); ts += sc0[r];
            sc1[r] = exp2f(sc1[r] - mst); ts += sc1[r];
        }
        ts += __shfl_xor(ts, 32);
        lst += ts;

        unsigned a0 = cvtpk(sc0[0], sc0[1]),   b0 = cvtpk(sc0[4], sc0[5]);   pswap(a0, b0);
        unsigned a1 = cvtpk(sc0[2], sc0[3]),   b1 = cvtpk(sc0[6], sc0[7]);   pswap(a1, b1);
        unsigned a2 = cvtpk(sc0[8], sc0[9]),   b2 = cvtpk(sc0[12], sc0[13]); pswap(a2, b2);
        unsigned a3 = cvtpk(sc0[10], sc0[11]), b3 = cvtpk(sc0[14], sc0[15]); pswap(a3, b3);
        bf16x8 pa00 = mkpa(a0, a1, b0, b1);
        bf16x8 pa01 = mkpa(a2, a3, b2, b3);
        unsigned c0 = cvtpk(sc1[0], sc1[1]),   d0 = cvtpk(sc1[4], sc1[5]);   pswap(c0, d0);
        unsigned c1 = cvtpk(sc1[2], sc1[3]),   d1 = cvtpk(sc1[6], sc1[7]);   pswap(c1, d1);
        unsigned c2 = cvtpk(sc1[8], sc1[9]),   d2 = cvtpk(sc1[12], sc1[13]); pswap(c2, d2);
        unsigned c3 = cvtpk(sc1[10], sc1[11]), d3 = cvtpk(sc1[14], sc1[15]); pswap(c3, d3);
        bf16x8 pa10 = mkpa(c0, c1, d0, d1);
        bf16x8 pa11 = mkpa(c2, c3, d2, d3);

        __builtin_amdgcn_s_setprio(1);
        acc0 = __builtin_amdgcn_mfma_f32_32x32x16_bf16(pa00, vac[0][0], acc0, 0, 0, 0);
        acc1 = __builtin_amdgcn_mfma_f32_32x32x16_bf16(pa00, vac[1][0], acc1, 0, 0, 0);
        acc0 = __builtin_amdgcn_mfma_f32_32x32x16_bf16(pa01, vac[0][1], acc0, 0, 0, 0);
        acc1 = __builtin_amdgcn_mfma_f32_32x32x16_bf16(pa01, vac[1][1], acc1, 0, 0, 0);
        acc0 = __builtin_amdgcn_mfma_f32_32x32x16_bf16(pa10, vac[0][2], acc0, 0, 0, 0);
        acc1 = __builtin_amdgcn_mfma_f32_32x32x16_bf16(pa10, vac[1][2], acc1, 0, 0, 0);
        acc0 = __builtin_amdgcn_mfma_f32_32x32x16_bf16(pa11, vac[0][3], acc0, 0, 0, 0);
        acc1 = __builtin_amdgcn_mfma_f32_32x32x16_bf16(pa11, vac[1][3], acc1, 0, 0, 0);
        __builtin_amdgcn_s_setprio(0);

        if (kt + 1 < kt1) {
            #pragma unroll
            for (int kh = 0; kh < 2; ++kh)
                #pragma unroll
                for (int c = 0; c < 4; ++c) kac[kh][c] = kan[kh][c];
        }
    }

    // merge wave1 partials into wave0, then wave0 writes
    if (wv_ == 1) {
        #pragma unroll
        for (int r = 0; r < 16; ++r) {
            const int cr = (r & 3) + (hi << 2) + ((r >> 2) << 3);
            Om[cr][x] = acc0[r];
            Om[cr][32 + x] = acc1[r];
        }
        if (lane < 32) { Ml[0][lane] = mst; Ml[1][lane] = lst; }
    }
    __syncthreads();
    if (wv_ == 0) {
        const float m1 = Ml[0][x], l1 = Ml[1][x];
        const float m = fmaxf(mst, m1);
        const float a = exp2f(mst - m);
        const float bb = exp2f(m1 - m);
        const float li = 1.f / (lst * a + l1 * bb);
        #pragma unroll
        for (int r = 0; r < 16; ++r) {
            const int cr = (r & 3) + (hi << 2) + ((r >> 2) << 3);
            const float aw = __shfl(a, cr);
            const float bw = __shfl(bb, cr);
            const float lw = __shfl(li, cr);
            const int q = sW + cr;
            const size_t rowb = ((size_t)b * S_LEN + q) * DM + h * DKH;
            ctx16[rowb + x] = f2b((acc0[r] * aw + Om[cr][x] * bw) * lw);
            ctx16[rowb + 32 + x] = f2b((acc1[r] * aw + Om[cr][32 + x] * bw) * lw);
        }
    }
}

// ---------------- row LayerNorm (LN1), optional bf16 copy ----------------
template <int EB16>
__global__ __launch_bounds__(256) void layernorm_kernel(
    const float* __restrict__ in, const float* __restrict__ gam, const float* __restrict__ bet,
    float* __restrict__ outf, unsigned short* __restrict__ outb) {
    __shared__ float red[8];
    const int row = blockIdx.x, t = threadIdx.x;
    const int wave = t >> 6, lane = t & 63;
    const float* p = in + (size_t)row * DM;
    const float v0 = p[t], v1 = p[t + 256], v2 = p[t + 512];
    float s = v0 + v1 + v2;
    float sq = v0 * v0 + v1 * v1 + v2 * v2;
    #pragma unroll
    for (int off = 32; off > 0; off >>= 1) { s += __shfl_xor(s, off); sq += __shfl_xor(sq, off); }
    if (lane == 0) { red[wave] = s; red[wave + 4] = sq; }
    __syncthreads();
    s = red[0] + red[1] + red[2] + red[3];
    sq = red[4] + red[5] + red[6] + red[7];
    const float mu = s * (1.f / DM);
    const float var = sq * (1.f / DM) - mu * mu;
    const float rs = rsqrtf(var + 1e-5f);
    #pragma unroll
    for (int i = 0; i < 3; ++i) {
        const int c = t + i * 256;
        const float vv = (i == 0 ? v0 : (i == 1 ? v1 : v2));
        const float y = (vv - mu) * rs * gam[c] + bet[c];
        outf[(size_t)row * DM + c] = y;
        if (EB16) outb[(size_t)row * DM + c] = f2b(y);
    }
}

// ---------------- LN2 fused with split-K merge ----------------
__global__ __launch_bounds__(256) void ln2_merge_kernel(
    const float* __restrict__ part, size_t pstride, int ns,
    const float* __restrict__ res, const float* __restrict__ bias,
    const float* __restrict__ gam, const float* __restrict__ bet,
    float* __restrict__ outf) {
    __shared__ float red[8];
    const int row = blockIdx.x, t = threadIdx.x;
    const int wave = t >> 6, lane = t & 63;
    float v[3];
    #pragma unroll
    for (int i = 0; i < 3; ++i) {
        const int c = t + i * 256;
        float sv = res[(size_t)row * DM + c] + bias[c];
        for (int z = 0; z < ns; ++z)
            sv += part[(size_t)z * pstride + (size_t)row * DM + c];
        v[i] = sv;
    }
    float s = v[0] + v[1] + v[2];
    float sq = v[0] * v[0] + v[1] * v[1] + v[2] * v[2];
    #pragma unroll
    for (int off = 32; off > 0; off >>= 1) { s += __shfl_xor(s, off); sq += __shfl_xor(sq, off); }
    if (lane == 0) { red[wave] = s; red[wave + 4] = sq; }
    __syncthreads();
    s = red[0] + red[1] + red[2] + red[3];
    sq = red[4] + red[5] + red[6] + red[7];
    const float mu = s * (1.f / DM);
    const float var = sq * (1.f / DM) - mu * mu;
    const float rs = rsqrtf(var + 1e-5f);
    #pragma unroll
    for (int i = 0; i < 3; ++i) {
        const int c = t + i * 256;
        outf[(size_t)row * DM + c] = (v[i] - mu) * rs * gam[c] + bet[c];
    }
}

extern "C" void kernel_launch(void* const* d_in, const int* in_sizes, int n_in,
                              void* d_out, int out_size, void* d_ws, size_t ws_size,
                              hipStream_t stream) {
    const float* x   = (const float*)d_in[0];
    const float* wq  = (const float*)d_in[1];
    const float* bq  = (const float*)d_in[2];
    const float* wk  = (const float*)d_in[3];
    const float* bk  = (const float*)d_in[4];
    const float* wv  = (const float*)d_in[5];
    const float* bv  = (const float*)d_in[6];
    const float* wo  = (const float*)d_in[7];
    const float* bo  = (const float*)d_in[8];
    const float* w1  = (const float*)d_in[9];
    const float* b1  = (const float*)d_in[10];
    const float* w2  = (const float*)d_in[11];
    const float* b2  = (const float*)d_in[12];
    const float* g1  = (const float*)d_in[13];
    const float* be1 = (const float*)d_in[14];
    const float* g2  = (const float*)d_in[15];
    const float* be2 = (const float*)d_in[16];

    char* wp = (char*)d_ws;
    auto alloc = [&](size_t bytes) -> void* {
        void* r = (void*)wp;
        wp += (bytes + 255) & ~(size_t)255;
        return r;
    };
    const int M = MROWS;
    unsigned short* wqkv16 = (unsigned short*)alloc((size_t)3 * DM * DM * 2);  // [2304][768]
    unsigned short* wo16 = (unsigned short*)alloc((size_t)DM * DM * 2);
    unsigned short* w116 = (unsigned short*)alloc((size_t)DM * DFF * 2);
    unsigned short* w216 = (unsigned short*)alloc((size_t)DM * DFF * 2);
    unsigned short* ctx16 = (unsigned short*)alloc((size_t)M * DM * 2);
    float* y1 = (float*)alloc((size_t)M * DM * 4);
    unsigned short* x16  = (unsigned short*)alloc((size_t)M * DM * 2);
    unsigned short* q16  = (unsigned short*)alloc((size_t)M * DM * 2);
    unsigned short* k16  = (unsigned short*)alloc((size_t)M * DM * 2);
    unsigned short* vt16 = (unsigned short*)alloc((size_t)M * DM * 2);
    unsigned short* ff116 = x16;    // [M,DFF] bf16 over x16..vt16 (contiguous, dead after attn)
    unsigned short* x116  = ctx16;  // LN1 bf16 output

    const size_t per = (size_t)M * DM * 4;
    size_t used = (size_t)(wp - (char*)d_ws);
    int NS = 1;
    if (used + 4 * per + 1024 <= ws_size) NS = 4;
    else if (used + 2 * per + 1024 <= ws_size) NS = 2;
    float* part = (float*)alloc((size_t)NS * per);

    prep_kernel<<<9984, 256, 0, stream>>>(x, wq, wk, wv, wo, w1, w2,
                                          x16, wqkv16, wo16, w116, w216);

    const float QSCALE = 0.125f * 1.44269504088896f;
    // QKV: 256x192 tile, N=2304 -> 12x16 = 192 blocks
    gemm192<1><<<dim3(3 * DM / 192, M / 256), 512, 0, stream>>>(
        x16, DM, wqkv16, DM, bq, bk, bv, q16, k16, vt16, nullptr, M, 3 * DM, DM, QSCALE);

    attn_mfma_kernel<<<dim3(BATCH * NH, S_LEN / 32), 128, 0, stream>>>(q16, k16, vt16, ctx16);

    gemm_bt64<0, 1, 1, 0><<<dim3(DM / 64, M / 128), 256, 0, stream>>>(
        ctx16, wo16, bo, x, y1, nullptr, M, DM, DM);
    layernorm_kernel<1><<<M, 256, 0, stream>>>(y1, g1, be1, y1, x116);

    // FFN1: N=3072 -> 16x16 = 256 blocks (100% fill)
    gemm192<0><<<dim3(DFF / 192, M / 256), 512, 0, stream>>>(
        x116, DM, w116, DM, b1, nullptr, nullptr, ff116, nullptr, nullptr, nullptr, M, DFF, DM, 1.f);

    // FFN2: N=768 -> 4x16xNS blocks (NS=4 -> 256, 100% fill)
    gemm192<2><<<dim3(DM / 192, M / 256, NS), 512, 0, stream>>>(
        ff116, DFF, w216, DFF, nullptr, nullptr, nullptr, nullptr, nullptr, nullptr, part,
        M, DM, DFF / NS, 1.f);
    ln2_merge_kernel<<<M, 256, 0, stream>>>(part, per / 4, NS, y1, b2, g2, be2, (float*)d_out);
}